// Round 4
// baseline (449.875 us; speedup 1.0000x reference)
//
#include <hip/hip_runtime.h>
#include <stdint.h>

typedef __bf16 bf16x8 __attribute__((ext_vector_type(8)));
typedef float f32x4 __attribute__((ext_vector_type(4)));

#define BB 8
#define SS 2048
#define HH 1024

// compact triangular scores: 256x256 tiles, row slot = 1024B (fp32) / first
// 512B (bf16 after softmax). 8x8 tile grid -> 36 lower tiles per batch.
#define T256     262144ll
#define NTRI256  36
#define BATCH256 (NTRI256 * T256)   // 9,437,184 B per batch

// ws layout (bytes). Peak ~169 MiB.
// Q [0,32M) | K [32M,64M) | Vt [64M,96M) | mask 16K | meanV 32K | TMP [97M..)
// TMP phase A: Xbf(32M)+Wbf(6M)+V(32M); TMP phase B: scores 8*9M = 72 MiB
#define OFF_Q      0ll
#define OFF_K      33554432ll
#define OFF_VT     67108864ll
#define OFF_MASK   100663296ll
#define OFF_MEANV  100679680ll
#define OFF_TMP    101711872ll
#define OFF_XBF    (OFF_TMP)
#define OFF_WBF    (OFF_TMP + 33554432ll)
#define OFF_V      (OFF_TMP + 39845888ll)
#define OFF_SCORES (OFF_TMP)

__device__ __forceinline__ unsigned short f2bf(float f) {
  unsigned int u = __float_as_uint(f);
  u += 0x7FFFu + ((u >> 16) & 1u);   // RTNE
  return (unsigned short)(u >> 16);
}
__device__ __forceinline__ float bf2f(unsigned short u) {
  return __uint_as_float(((unsigned int)u) << 16);
}

__device__ __forceinline__ void gl_lds16(const void* g, void* l) {
  __builtin_amdgcn_global_load_lds(
      (const __attribute__((address_space(1))) void*)g,
      (__attribute__((address_space(3))) void*)l, 16, 0, 0);
}

// ---------------- mask canonicalizer (uint8 / int32 / float32) --------------
__global__ void canon_mask(const unsigned char* __restrict__ m,
                           unsigned char* __restrict__ out, int n) {
  __shared__ int cnt[4];
  const int t = threadIdx.x;
  if (t < 4) cnt[t] = 0;
  __syncthreads();
  int loc[4] = {0, 0, 0, 0};
  for (int i = t; i < n; i += 256)
    if (m[i] != 0) loc[i & 3]++;
  for (int r = 0; r < 4; ++r)
    if (loc[r]) atomicAdd(&cnt[r], loc[r]);
  __syncthreads();
  const int c0 = cnt[0], c1 = cnt[1], c2 = cnt[2], c3 = cnt[3];
  if (c0 > 0 && c1 == 0 && c2 == 0 && c3 == 0) {        // int32 0/1
    const int* mi = (const int*)m;
    for (int i = t; i < n; i += 256) out[i] = mi[i] ? 1 : 0;
  } else if (c0 == 0 && (c2 > 0 || c3 > 0)) {           // float32
    const float* mf = (const float*)m;
    for (int i = t; i < n; i += 256) out[i] = (mf[i] != 0.0f) ? 1 : 0;
  } else {                                              // uint8 bool
    for (int i = t; i < n; i += 256) out[i] = m[i] ? 1 : 0;
  }
}

__global__ void cvt_f32_bf16(const float* __restrict__ in,
                             unsigned short* __restrict__ out, int n4) {
  int i = blockIdx.x * blockDim.x + threadIdx.x;
  int stride = gridDim.x * blockDim.x;
  for (; i < n4; i += stride) {
    float4 v = ((const float4*)in)[i];
    ushort4 o;
    o.x = f2bf(v.x); o.y = f2bf(v.y); o.z = f2bf(v.z); o.w = f2bf(v.w);
    ((ushort4*)out)[i] = o;
  }
}

// V [S,H] -> Vt [H,S] per batch
__global__ void transpose_v(const unsigned short* __restrict__ V,
                            unsigned short* __restrict__ Vt) {
  __shared__ unsigned short t[32][33];
  int b = blockIdx.z;
  const unsigned short* Vb = V + (size_t)b * SS * HH;
  unsigned short* Vtb = Vt + (size_t)b * SS * HH;
  int x0 = blockIdx.x * 32, y0 = blockIdx.y * 32;
  int tx = threadIdx.x, ty = threadIdx.y;
#pragma unroll
  for (int i = 0; i < 4; ++i)
    t[ty + i * 8][tx] = Vb[(size_t)(y0 + ty + i * 8) * HH + x0 + tx];
  __syncthreads();
#pragma unroll
  for (int i = 0; i < 4; ++i)
    Vtb[(size_t)(x0 + ty + i * 8) * SS + y0 + tx] = t[tx][ty + i * 8];
}

__global__ __launch_bounds__(256) void meanv_sum(
    const unsigned short* __restrict__ Vt, float* __restrict__ out) {
  const int b = blockIdx.y;
  const int wave = threadIdx.x >> 6, lane = threadIdx.x & 63;
  const int h = blockIdx.x * 4 + wave;
  const unsigned short* row = Vt + ((long)b * HH + h) * SS;
  float s = 0.f;
#pragma unroll
  for (int j = 0; j < 4; ++j) {
    const ushort4* p = (const ushort4*)(row + j * 512 + lane * 8);
    ushort4 u0 = p[0], u1 = p[1];
    s += bf2f(u0.x) + bf2f(u0.y) + bf2f(u0.z) + bf2f(u0.w)
       + bf2f(u1.x) + bf2f(u1.y) + bf2f(u1.z) + bf2f(u1.w);
  }
#pragma unroll
  for (int off = 32; off > 0; off >>= 1) s += __shfl_down(s, off, 64);
  if (lane == 0) out[(long)b * HH + h] = s;
}

__global__ __launch_bounds__(256) void fixup_masked(
    float* __restrict__ out, const unsigned char* __restrict__ mask,
    const float* __restrict__ sums) {
  const long row = blockIdx.x;
  if (mask[row]) return;
  const long b = row >> 11;
  const int t = threadIdx.x;
  float4 v = ((const float4*)(sums + b * HH))[t];
  v.x *= (1.f / 2048.f); v.y *= (1.f / 2048.f);
  v.z *= (1.f / 2048.f); v.w *= (1.f / 2048.f);
  ((float4*)(out + row * HH))[t] = v;
}

// ------------- 256x256 GEMM, BK=32, ring-4 LDS, counted vmcnt ---------------
// C[m,n] = sum_k A[m,k]*B[n,k], K=1024 (NT=32 K-tiles). 512 thr = 8 waves
// (2 Mx4 N); wave tile 128x64; acc 8x4 f32x4. LDS: 4 bufs x (A 16K + B 16K).
// Schedule: stage tile t+3 into buf[(t+3)&3] during phase t (buffer last read
// in phase t-1 -> issue after its barrier => no WAR); vmcnt(8) leaves tiles
// t+2,t+3 in flight (never drains to 0 in-loop); 1 barrier / 32 MFMA.
// MODE 0: fused QKV (z=matrix); MODE 1: scores (z=batch, triangular blockIdx.x)
template <int MODE>
__global__ __launch_bounds__(512, 2) void gemm256(
    const unsigned short* __restrict__ Abase, long aStride,
    const unsigned short* __restrict__ Bbase, long bStride,
    char* __restrict__ Cq, char* __restrict__ Ck, char* __restrict__ Cv,
    const float* __restrict__ biasq, const float* __restrict__ biask,
    const float* __restrict__ biasv,
    const unsigned char* __restrict__ maskg, char* __restrict__ scoresBase) {
  extern __shared__ char smem[];
  const int tid = threadIdx.x;
  const int wave = tid >> 6, lane = tid & 63;
  const int wr = wave >> 2, wc = wave & 3;
  const int l15 = lane & 15, l4 = lane >> 4;
  const int bz = blockIdx.z;

  int bm, bn, triIdx = 0;
  if (MODE == 1) {
    int t = blockIdx.x, m_ = 0, a_ = 0;
    while (a_ + m_ + 1 <= t) { ++m_; a_ += m_; }
    bm = m_; bn = t - a_; triIdx = t;
  } else {
    bm = blockIdx.x; bn = blockIdx.y;
  }

  const unsigned short* A = (MODE == 1) ? Abase + (long)bz * aStride : Abase;
  const unsigned short* B = Bbase + (long)bz * bStride;  // MODE0: z picks W

  // staging: thread covers 16B at LDS linear off c*8192 + tid*16 per chunk;
  // row = c*128 + tid>>2, colb = (tid&3)*16 of the [256][64B] K-major tile.
  const int srow = tid >> 2;
  const int scol = (tid & 3) << 4;
  const char* aS0 = (const char*)A + (long)(bm * 256 + srow) * 2048 + scol;
  const char* aS1 = (const char*)A + (long)(bm * 256 + 128 + srow) * 2048 + scol;
  const char* bS0 = (const char*)B + (long)(bn * 256 + srow) * 2048 + scol;
  const char* bS1 = (const char*)B + (long)(bn * 256 + 128 + srow) * 2048 + scol;
  const int ldsW = wave << 10;

#define STAGE256(t_) do { \
    char* _p = smem + (((t_) & 3) << 15); \
    const long _ko = (long)(t_) << 6; \
    gl_lds16(aS0 + _ko, _p + ldsW); \
    gl_lds16(aS1 + _ko, _p + 8192 + ldsW); \
    gl_lds16(bS0 + _ko, _p + 16384 + ldsW); \
    gl_lds16(bS1 + _ko, _p + 24576 + ldsW); } while (0)

  // per-lane fragment read offsets ([256][64B] rows): frag m at +m*1024
  const int rdA = ((wr << 7) + l15) * 64 + (l4 << 4);
  const int rdB = 16384 + ((wc << 6) + l15) * 64 + (l4 << 4);

  f32x4 acc[8][4];
  const f32x4 z4 = {0.f, 0.f, 0.f, 0.f};
#pragma unroll
  for (int m = 0; m < 8; ++m)
#pragma unroll
    for (int n = 0; n < 4; ++n) acc[m][n] = z4;

  STAGE256(0); STAGE256(1); STAGE256(2);
  asm volatile("s_waitcnt vmcnt(8)" ::: "memory");  // tile 0 landed
  __builtin_amdgcn_s_barrier();
  __builtin_amdgcn_sched_barrier(0);

  for (int t = 0; t < 32; ++t) {
    if (t < 29) STAGE256(t + 3);
    const char* bufp = smem + ((t & 3) << 15);
    bf16x8 af[8], bg[4];
#pragma unroll
    for (int m = 0; m < 8; ++m)
      af[m] = *(const bf16x8*)(bufp + rdA + m * 1024);
#pragma unroll
    for (int n = 0; n < 4; ++n)
      bg[n] = *(const bf16x8*)(bufp + rdB + n * 1024);
    __builtin_amdgcn_s_setprio(1);
#pragma unroll
    for (int m = 0; m < 8; ++m)
#pragma unroll
      for (int n = 0; n < 4; ++n)
        acc[m][n] = __builtin_amdgcn_mfma_f32_16x16x32_bf16(af[m], bg[n],
                                                            acc[m][n], 0, 0, 0);
    __builtin_amdgcn_s_setprio(0);
    __builtin_amdgcn_sched_barrier(0);
    if (t < 29)       asm volatile("s_waitcnt vmcnt(8)" ::: "memory");
    else if (t == 29) asm volatile("s_waitcnt vmcnt(4)" ::: "memory");
    else if (t == 30) asm volatile("s_waitcnt vmcnt(0)" ::: "memory");
    if (t < 31) {
      __builtin_amdgcn_s_barrier();
      __builtin_amdgcn_sched_barrier(0);
      asm volatile("" ::: "memory");
    }
  }

  if (MODE == 0) {
    const float* bias = (bz == 0) ? biasq : (bz == 1) ? biask : biasv;
    unsigned short* C = (unsigned short*)((bz == 0) ? Cq : (bz == 1) ? Ck : Cv);
    const int row0 = bm * 256 + (wr << 7);
    const int col0 = bn * 256 + (wc << 6);
#pragma unroll
    for (int n = 0; n < 4; ++n) {
      const int col = col0 + n * 16 + l15;
      const float bv = bias[col];
#pragma unroll
      for (int m = 0; m < 8; ++m)
#pragma unroll
        for (int r = 0; r < 4; ++r) {
          const int row = row0 + m * 16 + l4 * 4 + r;
          C[(long)row * HH + col] = f2bf(acc[m][n][r] + bv);
        }
    }
  } else {
    float* Ct = (float*)(scoresBase + (long)bz * BATCH256 + (long)triIdx * T256);
    const unsigned char* mrow = maskg + (long)bz * SS;
    const int row0l = wr << 7, col0l = wc << 6;
#pragma unroll
    for (int m = 0; m < 8; ++m)
#pragma unroll
      for (int r = 0; r < 4; ++r) {
        const int ql = row0l + m * 16 + l4 * 4 + r;
        const int q = bm * 256 + ql;
        const bool qm = mrow[q] != 0;
#pragma unroll
        for (int n = 0; n < 4; ++n) {
          const int kl = col0l + n * 16 + l15;
          const int k = bn * 256 + kl;
          float v;
          if (!qm) v = 0.0f;               // fixup overwrites these rows
          else if (k <= q && mrow[k]) v = acc[m][n][r] * 0.03125f;
          else v = -1.0e9f;
          Ct[ql * 256 + kl] = v;
        }
      }
  }
#undef STAGE256
}

// ---------------- softmax over causal prefix, compact 256-tiles -------------
__global__ __launch_bounds__(256) void softmax_tri(char* __restrict__ base) {
  const int r = blockIdx.x;            // row within batch
  const int bz = blockIdx.y;
  const int bm = r >> 8;
  const int w = (bm + 1) << 8;         // causal prefix width
  char* bb = base + (long)bz * BATCH256 +
             (long)(bm * (bm + 1) / 2) * T256 + (long)(r & 255) * 1024;
  const int t = threadIdx.x;
  const bool act = (t << 3) < w;
  const int bn = t >> 5;
  const int cl = (t << 3) & 255;
  const char* src = bb + (long)bn * T256 + (long)cl * 4;
  float v[8];
  float m = -3.0e38f;
  if (act) {
    float4 a = ((const float4*)src)[0];
    float4 b2 = ((const float4*)src)[1];
    v[0] = a.x; v[1] = a.y; v[2] = a.z; v[3] = a.w;
    v[4] = b2.x; v[5] = b2.y; v[6] = b2.z; v[7] = b2.w;
#pragma unroll
    for (int k = 0; k < 8; ++k) m = fmaxf(m, v[k]);
  }
  __shared__ float red[8];
#pragma unroll
  for (int off = 32; off > 0; off >>= 1) m = fmaxf(m, __shfl_down(m, off, 64));
  const int wid = t >> 6, lane = t & 63;
  if (lane == 0) red[wid] = m;
  __syncthreads();
  m = fmaxf(fmaxf(red[0], red[1]), fmaxf(red[2], red[3]));
  float e[8];
  float s = 0.f;
  if (act) {
#pragma unroll
    for (int k = 0; k < 8; ++k) { e[k] = __expf(v[k] - m); s += e[k]; }
  }
#pragma unroll
  for (int off = 32; off > 0; off >>= 1) s += __shfl_down(s, off, 64);
  if (lane == 0) red[4 + wid] = s;
  __syncthreads();
  s = red[4] + red[5] + red[6] + red[7];
  const float inv = 1.0f / s;
  if (act) {
    ushort4 o0, o1;
    o0.x = f2bf(e[0] * inv); o0.y = f2bf(e[1] * inv);
    o0.z = f2bf(e[2] * inv); o0.w = f2bf(e[3] * inv);
    o1.x = f2bf(e[4] * inv); o1.y = f2bf(e[5] * inv);
    o1.z = f2bf(e[6] * inv); o1.w = f2bf(e[7] * inv);
    ushort4* dst = (ushort4*)(bb + (long)bn * T256 + (long)cl * 2);
    dst[0] = o0;
    dst[1] = o1;
  }
}

// ---------------- PV: 128x128 m97 core over compact attn --------------------
__global__ __launch_bounds__(256) void gemm_pv(
    const char* __restrict__ attn, const unsigned short* __restrict__ VtB,
    float* __restrict__ Out) {
  const int bz = blockIdx.z;
  const int bm = blockIdx.x, bn = blockIdx.y;
  const int R = bm >> 1;               // 256-tile row
  const char* Ab = attn + (long)bz * BATCH256 + (long)(R * (R + 1) / 2) * T256;
  const unsigned short* B = VtB + (long)bz * SS * HH;

  __shared__ unsigned short As[128 * 32];
  __shared__ unsigned short Bs[128 * 32];

  const int tid = threadIdx.x;
  const int wave = tid >> 6;
  const int lane = tid & 63;
  const int wr = wave >> 1, wc = wave & 1;
  const int lr = lane >> 4, lc = lane & 15;

  f32x4 acc[4][4];
  const f32x4 z4 = {0.f, 0.f, 0.f, 0.f};
#pragma unroll
  for (int i = 0; i < 4; ++i)
#pragma unroll
    for (int j = 0; j < 4; ++j) acc[i][j] = z4;

  const int r0 = tid >> 2;
  const int c8 = (tid & 3) * 8;
  const char* aP0 = Ab + (long)((bm & 1) * 128 + r0) * 1024 + c8 * 2;
  const char* aP1 = Ab + (long)((bm & 1) * 128 + r0 + 64) * 1024 + c8 * 2;
  const unsigned short* bS0 = B + (long)(bn * 128 + r0) * SS + c8;
  const unsigned short* bS1 = B + (long)(bn * 128 + r0 + 64) * SS + c8;
  char* asL0 = (char*)As + wave * 1024;
  char* asL1 = (char*)As + 4096 + wave * 1024;
  char* bsL0 = (char*)Bs + wave * 1024;
  char* bsL1 = (char*)Bs + 4096 + wave * 1024;

  const int kTiles = (R + 1) * 8;
  for (int kt = 0; kt < kTiles; ++kt) {
    const int ko = kt * 32;
    const long offA = (long)(ko >> 8) * T256 + ((ko & 255) << 1);
    __syncthreads();
    gl_lds16(aP0 + offA, asL0);
    gl_lds16(aP1 + offA, asL1);
    gl_lds16((const void*)(bS0 + ko), bsL0);
    gl_lds16((const void*)(bS1 + ko), bsL1);
    __syncthreads();
    bf16x8 af[4], bg[4];
#pragma unroll
    for (int i = 0; i < 4; ++i)
      af[i] = *(const bf16x8*)(const void*)&As[(wr * 64 + i * 16 + lc) * 32 + lr * 8];
#pragma unroll
    for (int j = 0; j < 4; ++j)
      bg[j] = *(const bf16x8*)(const void*)&Bs[(wc * 64 + j * 16 + lc) * 32 + lr * 8];
#pragma unroll
    for (int i = 0; i < 4; ++i)
#pragma unroll
      for (int j = 0; j < 4; ++j)
        acc[i][j] = __builtin_amdgcn_mfma_f32_16x16x32_bf16(af[i], bg[j],
                                                            acc[i][j], 0, 0, 0);
  }

#pragma unroll
  for (int i = 0; i < 4; ++i)
#pragma unroll
    for (int j = 0; j < 4; ++j)
#pragma unroll
      for (int r = 0; r < 4; ++r) {
        const int row = bm * 128 + wr * 64 + i * 16 + lr * 4 + r;
        const int col = bn * 128 + wc * 64 + j * 16 + lc;
        Out[((long)bz * SS + row) * HH + col] = acc[i][j][r];
      }
}

extern "C" void kernel_launch(void* const* d_in, const int* in_sizes, int n_in,
                              void* d_out, int out_size, void* d_ws, size_t ws_size,
                              hipStream_t stream) {
  (void)in_sizes; (void)n_in; (void)out_size; (void)ws_size;
  const float* x = (const float*)d_in[0];
  const unsigned char* mask_raw = (const unsigned char*)d_in[1];
  const float* Wq = (const float*)d_in[2];
  const float* bq = (const float*)d_in[3];
  const float* Wk = (const float*)d_in[4];
  const float* bk = (const float*)d_in[5];
  const float* Wv = (const float*)d_in[6];
  const float* bv = (const float*)d_in[7];
  char* ws = (char*)d_ws;

  unsigned short* Xbf = (unsigned short*)(ws + OFF_XBF);
  unsigned short* Wbf = (unsigned short*)(ws + OFF_WBF);
  unsigned short* Qb = (unsigned short*)(ws + OFF_Q);
  unsigned short* Kb = (unsigned short*)(ws + OFF_K);
  unsigned short* Vb = (unsigned short*)(ws + OFF_V);
  unsigned short* Vt = (unsigned short*)(ws + OFF_VT);
  unsigned char* mask = (unsigned char*)(ws + OFF_MASK);
  float* meanV = (float*)(ws + OFF_MEANV);

  const long MS = (long)BB * SS;  // 16384

  // allow 128 KiB dynamic LDS for gemm256 (idempotent host-side call)
  (void)hipFuncSetAttribute((const void*)gemm256<0>,
                            hipFuncAttributeMaxDynamicSharedMemorySize, 131072);
  (void)hipFuncSetAttribute((const void*)gemm256<1>,
                            hipFuncAttributeMaxDynamicSharedMemorySize, 131072);

  // 0. canonicalize mask
  canon_mask<<<1, 256, 0, stream>>>(mask_raw, mask, (int)(BB * SS));

  // 1. fp32 -> bf16
  cvt_f32_bf16<<<2048, 256, 0, stream>>>(x, Xbf, (int)(MS * HH / 4));
  cvt_f32_bf16<<<256, 256, 0, stream>>>(Wq, Wbf, HH * HH / 4);
  cvt_f32_bf16<<<256, 256, 0, stream>>>(Wk, Wbf + HH * HH, HH * HH / 4);
  cvt_f32_bf16<<<256, 256, 0, stream>>>(Wv, Wbf + 2 * HH * HH, HH * HH / 4);

  // 2. fused QKV projection (256^2 core): grid (64,4,3)
  gemm256<0><<<dim3(MS / 256, HH / 256, 3), 512, 131072, stream>>>(
      Xbf, 0, Wbf, (long)HH * HH,
      (char*)Qb, (char*)Kb, (char*)Vb, bq, bk, bv, nullptr, nullptr);

  // 3. V -> Vt ; column sums for masked-row fixup
  transpose_v<<<dim3(HH / 32, SS / 32, BB), dim3(32, 8), 0, stream>>>(Vb, Vt);
  meanv_sum<<<dim3(HH / 4, BB), 256, 0, stream>>>(Vt, meanV);

  // 4. scores: triangular 256^2 tiles, all batches: grid (36,1,8)
  gemm256<1><<<dim3(NTRI256, 1, BB), 512, 131072, stream>>>(
      Qb, (long)SS * HH, Kb, (long)SS * HH,
      nullptr, nullptr, nullptr, nullptr, nullptr, nullptr,
      mask, ws + OFF_SCORES);

  // 5. softmax over causal prefix, in-place -> compact bf16
  softmax_tri<<<dim3(SS, BB), 256, 0, stream>>>(ws + OFF_SCORES);

  // 6. out = attn @ V (compact A, causal K-limit)
  gemm_pv<<<dim3(SS / 128, HH / 128, BB), 256, 0, stream>>>(
      ws + OFF_SCORES, Vt, (float*)d_out);

  // 7. masked query rows -> uniform mean of V
  fixup_masked<<<BB * SS, 256, 0, stream>>>((float*)d_out, mask, meanV);
}

// Round 5
// 418.458 us; speedup vs baseline: 1.0751x; 1.0751x over previous
//
#include <hip/hip_runtime.h>
#include <stdint.h>

typedef __bf16 bf16x8 __attribute__((ext_vector_type(8)));
typedef float f32x4 __attribute__((ext_vector_type(4)));

#define BB 8
#define SS 2048
#define HH 1024

// compact triangular scores: 256x256 tiles, row slot = 1024B (fp32) / first
// 512B (bf16 after softmax). 8x8 tile grid -> 36 lower tiles per batch.
#define T256     262144ll
#define NTRI256  36
#define BATCH256 (NTRI256 * T256)   // 9,437,184 B per batch

// ws layout (bytes). Peak ~169 MiB (validated r4).
#define OFF_Q      0ll
#define OFF_K      33554432ll
#define OFF_VT     67108864ll
#define OFF_MASK   100663296ll
#define OFF_MEANV  100679680ll
#define OFF_TMP    101711872ll
#define OFF_XBF    (OFF_TMP)
#define OFF_WBF    (OFF_TMP + 33554432ll)
#define OFF_V      (OFF_TMP + 39845888ll)
#define OFF_SCORES (OFF_TMP)

__device__ __forceinline__ unsigned short f2bf(float f) {
  unsigned int u = __float_as_uint(f);
  u += 0x7FFFu + ((u >> 16) & 1u);   // RTNE
  return (unsigned short)(u >> 16);
}
__device__ __forceinline__ float bf2f(unsigned short u) {
  return __uint_as_float(((unsigned int)u) << 16);
}

__device__ __forceinline__ void gl_lds16(const void* g, void* l) {
  __builtin_amdgcn_global_load_lds(
      (const __attribute__((address_space(1))) void*)g,
      (__attribute__((address_space(3))) void*)l, 16, 0, 0);
}

// ---------------- mask canonicalizer (uint8 / int32 / float32) --------------
__global__ void canon_mask(const unsigned char* __restrict__ m,
                           unsigned char* __restrict__ out, int n) {
  __shared__ int cnt[4];
  const int t = threadIdx.x;
  if (t < 4) cnt[t] = 0;
  __syncthreads();
  int loc[4] = {0, 0, 0, 0};
  for (int i = t; i < n; i += 256)
    if (m[i] != 0) loc[i & 3]++;
  for (int r = 0; r < 4; ++r)
    if (loc[r]) atomicAdd(&cnt[r], loc[r]);
  __syncthreads();
  const int c0 = cnt[0], c1 = cnt[1], c2 = cnt[2], c3 = cnt[3];
  if (c0 > 0 && c1 == 0 && c2 == 0 && c3 == 0) {        // int32 0/1
    const int* mi = (const int*)m;
    for (int i = t; i < n; i += 256) out[i] = mi[i] ? 1 : 0;
  } else if (c0 == 0 && (c2 > 0 || c3 > 0)) {           // float32
    const float* mf = (const float*)m;
    for (int i = t; i < n; i += 256) out[i] = (mf[i] != 0.0f) ? 1 : 0;
  } else {                                              // uint8 bool
    for (int i = t; i < n; i += 256) out[i] = m[i] ? 1 : 0;
  }
}

__global__ void cvt_f32_bf16(const float* __restrict__ in,
                             unsigned short* __restrict__ out, int n4) {
  int i = blockIdx.x * blockDim.x + threadIdx.x;
  int stride = gridDim.x * blockDim.x;
  for (; i < n4; i += stride) {
    float4 v = ((const float4*)in)[i];
    ushort4 o;
    o.x = f2bf(v.x); o.y = f2bf(v.y); o.z = f2bf(v.z); o.w = f2bf(v.w);
    ((ushort4*)out)[i] = o;
  }
}

// V [S,H] -> Vt [H,S] per batch
__global__ void transpose_v(const unsigned short* __restrict__ V,
                            unsigned short* __restrict__ Vt) {
  __shared__ unsigned short t[32][33];
  int b = blockIdx.z;
  const unsigned short* Vb = V + (size_t)b * SS * HH;
  unsigned short* Vtb = Vt + (size_t)b * SS * HH;
  int x0 = blockIdx.x * 32, y0 = blockIdx.y * 32;
  int tx = threadIdx.x, ty = threadIdx.y;
#pragma unroll
  for (int i = 0; i < 4; ++i)
    t[ty + i * 8][tx] = Vb[(size_t)(y0 + ty + i * 8) * HH + x0 + tx];
  __syncthreads();
#pragma unroll
  for (int i = 0; i < 4; ++i)
    Vtb[(size_t)(x0 + ty + i * 8) * SS + y0 + tx] = t[tx][ty + i * 8];
}

__global__ __launch_bounds__(256) void meanv_sum(
    const unsigned short* __restrict__ Vt, float* __restrict__ out) {
  const int b = blockIdx.y;
  const int wave = threadIdx.x >> 6, lane = threadIdx.x & 63;
  const int h = blockIdx.x * 4 + wave;
  const unsigned short* row = Vt + ((long)b * HH + h) * SS;
  float s = 0.f;
#pragma unroll
  for (int j = 0; j < 4; ++j) {
    const ushort4* p = (const ushort4*)(row + j * 512 + lane * 8);
    ushort4 u0 = p[0], u1 = p[1];
    s += bf2f(u0.x) + bf2f(u0.y) + bf2f(u0.z) + bf2f(u0.w)
       + bf2f(u1.x) + bf2f(u1.y) + bf2f(u1.z) + bf2f(u1.w);
  }
#pragma unroll
  for (int off = 32; off > 0; off >>= 1) s += __shfl_down(s, off, 64);
  if (lane == 0) out[(long)b * HH + h] = s;
}

__global__ __launch_bounds__(256) void fixup_masked(
    float* __restrict__ out, const unsigned char* __restrict__ mask,
    const float* __restrict__ sums) {
  const long row = blockIdx.x;
  if (mask[row]) return;
  const long b = row >> 11;
  const int t = threadIdx.x;
  float4 v = ((const float4*)(sums + b * HH))[t];
  v.x *= (1.f / 2048.f); v.y *= (1.f / 2048.f);
  v.z *= (1.f / 2048.f); v.w *= (1.f / 2048.f);
  ((float4*)(out + row * HH))[t] = v;
}

// ------------- 256x256 GEMM, BK=32, ring-4 LDS, counted vmcnt, T2 swizzle ---
// LDS chunk = [128 rows][64B], swizzled placement:
//   A(row,c) = (row*64 + c*16) ^ ((row&7)<<4)        (c = 16B slot 0..3)
// gl_lds16 writes linearly (dest slot s = tid), so the GLOBAL source is
// inverse-permuted:  row = 2*(s>>3) | (((s>>2)&1)^((s>>4)&1)),
//                    c   = (s&3) ^ (row&3)            (bijective, verified)
// Reads use the same A(row,c): 16-lane groups hit all 8 16B slots -> 2-way.
// Ring-4: stage tile t+3 during phase t; vmcnt(8) leaves 2 tiles in flight.
// Epilogues bounce C through LDS for full-line coalesced global writes.
template <int MODE>
__global__ __launch_bounds__(512, 2) void gemm256(
    const unsigned short* __restrict__ Abase, long aStride,
    const unsigned short* __restrict__ Bbase, long bStride,
    char* __restrict__ Cq, char* __restrict__ Ck, char* __restrict__ Cv,
    const float* __restrict__ biasq, const float* __restrict__ biask,
    const float* __restrict__ biasv,
    const unsigned char* __restrict__ maskg, char* __restrict__ scoresBase) {
  extern __shared__ char smem[];
  const int tid = threadIdx.x;
  const int wave = tid >> 6, lane = tid & 63;
  const int wr = wave >> 2, wc = wave & 3;
  const int l15 = lane & 15, l4 = lane >> 4;
  const int bz = blockIdx.z;

  int bm, bn, triIdx = 0;
  if (MODE == 1) {
    int t = blockIdx.x, m_ = 0, a_ = 0;
    while (a_ + m_ + 1 <= t) { ++m_; a_ += m_; }
    bm = m_; bn = t - a_; triIdx = t;
  } else {
    bm = blockIdx.x; bn = blockIdx.y;
  }

  const unsigned short* A = (MODE == 1) ? Abase + (long)bz * aStride : Abase;
  const unsigned short* B = Bbase + (long)bz * bStride;  // MODE0: z picks W

  // inverse-swizzled staging source (linear LDS dest slot s = tid)
  const int s = tid;
  const int rA = ((s >> 3) << 1) | (((s >> 2) & 1) ^ ((s >> 4) & 1));
  const int cA = (s & 3) ^ (rA & 3);
  const char* aS0 = (const char*)A + (long)(bm * 256 + rA) * 2048 + cA * 16;
  const char* aS1 = (const char*)A + (long)(bm * 256 + 128 + rA) * 2048 + cA * 16;
  const char* bS0 = (const char*)B + (long)(bn * 256 + rA) * 2048 + cA * 16;
  const char* bS1 = (const char*)B + (long)(bn * 256 + 128 + rA) * 2048 + cA * 16;
  const int ldsW = wave << 10;

#define STAGE256(t_) do { \
    char* _p = smem + (((t_) & 3) << 15); \
    const long _ko = (long)(t_) << 6; \
    gl_lds16(aS0 + _ko, _p + ldsW); \
    gl_lds16(aS1 + _ko, _p + 8192 + ldsW); \
    gl_lds16(bS0 + _ko, _p + 16384 + ldsW); \
    gl_lds16(bS1 + _ko, _p + 24576 + ldsW); } while (0)

  // swizzled fragment read offsets (row&7 == l15&7 for all frags)
  const int baseSwz = ((l15 * 64 + (l4 << 4)) ^ ((l15 & 7) << 4));
  const int rdA = (wr << 13) + baseSwz;                    // + m*1024
  const int rdB = 16384 + (wc << 12) + baseSwz;            // + n*1024

  f32x4 acc[8][4];
  const f32x4 z4 = {0.f, 0.f, 0.f, 0.f};
#pragma unroll
  for (int m = 0; m < 8; ++m)
#pragma unroll
    for (int n = 0; n < 4; ++n) acc[m][n] = z4;

  STAGE256(0); STAGE256(1); STAGE256(2);
  asm volatile("s_waitcnt vmcnt(8)" ::: "memory");  // tile 0 landed
  __builtin_amdgcn_s_barrier();
  __builtin_amdgcn_sched_barrier(0);

  for (int t = 0; t < 32; ++t) {
    if (t < 29) STAGE256(t + 3);
    const char* bufp = smem + ((t & 3) << 15);
    bf16x8 af[8], bg[4];
#pragma unroll
    for (int m = 0; m < 8; ++m)
      af[m] = *(const bf16x8*)(bufp + rdA + (m << 10));
#pragma unroll
    for (int n = 0; n < 4; ++n)
      bg[n] = *(const bf16x8*)(bufp + rdB + (n << 10));
    __builtin_amdgcn_s_setprio(1);
#pragma unroll
    for (int m = 0; m < 8; ++m)
#pragma unroll
      for (int n = 0; n < 4; ++n)
        acc[m][n] = __builtin_amdgcn_mfma_f32_16x16x32_bf16(af[m], bg[n],
                                                            acc[m][n], 0, 0, 0);
    __builtin_amdgcn_s_setprio(0);
    __builtin_amdgcn_sched_barrier(0);
    if (t < 29)       asm volatile("s_waitcnt vmcnt(8)" ::: "memory");
    else if (t == 29) asm volatile("s_waitcnt vmcnt(4)" ::: "memory");
    else if (t == 30) asm volatile("s_waitcnt vmcnt(0)" ::: "memory");
    if (t < 31) {
      __builtin_amdgcn_s_barrier();
      __builtin_amdgcn_sched_barrier(0);
      asm volatile("" ::: "memory");
    }
  }
#undef STAGE256

  const int rl0 = (wr << 7) + (l4 << 2);   // local row base (+m*16+r)
  const int cl0 = (wc << 6) + l15;         // local col base (+n*16)

  if (MODE == 0) {
    const float* bias = (bz == 0) ? biasq : (bz == 1) ? biask : biasv;
    unsigned short* C = (unsigned short*)((bz == 0) ? Cq : (bz == 1) ? Ck : Cv);
    __syncthreads();                       // K-loop LDS reads done everywhere
    // acc -> LDS bf16 [256][256] (exactly 128 KiB)
#pragma unroll
    for (int n = 0; n < 4; ++n) {
      const int cl = cl0 + n * 16;
      const float bv = bias[bn * 256 + cl];
#pragma unroll
      for (int m = 0; m < 8; ++m) {
        const int rl = rl0 + m * 16;
#pragma unroll
        for (int r = 0; r < 4; ++r)
          *(unsigned short*)(smem + (rl + r) * 512 + cl * 2) =
              f2bf(acc[m][n][r] + bv);
      }
    }
    __syncthreads();
    // LDS -> global, full-line coalesced (32 x 16B per 512B row)
    const long rowg0 = (long)bm * 256;
    const long colb0 = (long)bn * 512;
#pragma unroll
    for (int i = 0; i < 16; ++i) {
      const int s2 = i * 512 + tid;
      const int row = s2 >> 5;
      const int colb = (s2 & 31) << 4;
      *(uint4*)((char*)C + (rowg0 + row) * 2048 + colb0 + colb) =
          *(const uint4*)(smem + (long)s2 * 16);
    }
  } else {
    char* Ct = scoresBase + (long)bz * BATCH256 + (long)triIdx * T256;
    const unsigned char* mrow = maskg + (long)bz * SS;
    bool km[4]; int kg[4];
#pragma unroll
    for (int n = 0; n < 4; ++n) {
      kg[n] = bn * 256 + cl0 + n * 16;
      km[n] = mrow[kg[n]] != 0;
    }
    // two 128-row halves (each 128 KiB fp32) through LDS
#pragma unroll
    for (int h = 0; h < 2; ++h) {
      __syncthreads();
      if (wr == h) {
#pragma unroll
        for (int m = 0; m < 8; ++m) {
#pragma unroll
          for (int r = 0; r < 4; ++r) {
            const int ql = rl0 + m * 16 + r;
            const int q = bm * 256 + ql;
            const bool qm = mrow[q] != 0;
            const int qh = ql & 127;
#pragma unroll
            for (int n = 0; n < 4; ++n) {
              float v;
              if (!qm) v = 0.0f;           // fixup overwrites these rows
              else if (kg[n] <= q && km[n]) v = acc[m][n][r] * 0.03125f;
              else v = -1.0e9f;
              *(float*)(smem + qh * 1024 + (cl0 + n * 16) * 4) = v;
            }
          }
        }
      }
      __syncthreads();
#pragma unroll
      for (int i = 0; i < 16; ++i) {
        const int s2 = i * 512 + tid;
        const int row = s2 >> 6;
        const int colb = (s2 & 63) << 4;
        *(uint4*)(Ct + (long)(h * 128 + row) * 1024 + colb) =
            *(const uint4*)(smem + (long)s2 * 16);
      }
    }
  }
}

// ---------------- softmax over causal prefix, compact 256-tiles -------------
__global__ __launch_bounds__(256) void softmax_tri(char* __restrict__ base) {
  const int r = blockIdx.x;            // row within batch
  const int bz = blockIdx.y;
  const int bm = r >> 8;
  const int w = (bm + 1) << 8;         // causal prefix width
  char* bb = base + (long)bz * BATCH256 +
             (long)(bm * (bm + 1) / 2) * T256 + (long)(r & 255) * 1024;
  const int t = threadIdx.x;
  const bool act = (t << 3) < w;
  const int bn = t >> 5;
  const int cl = (t << 3) & 255;
  const char* src = bb + (long)bn * T256 + (long)cl * 4;
  float v[8];
  float m = -3.0e38f;
  if (act) {
    float4 a = ((const float4*)src)[0];
    float4 b2 = ((const float4*)src)[1];
    v[0] = a.x; v[1] = a.y; v[2] = a.z; v[3] = a.w;
    v[4] = b2.x; v[5] = b2.y; v[6] = b2.z; v[7] = b2.w;
#pragma unroll
    for (int k = 0; k < 8; ++k) m = fmaxf(m, v[k]);
  }
  __shared__ float red[8];
#pragma unroll
  for (int off = 32; off > 0; off >>= 1) m = fmaxf(m, __shfl_down(m, off, 64));
  const int wid = t >> 6, lane = t & 63;
  if (lane == 0) red[wid] = m;
  __syncthreads();
  m = fmaxf(fmaxf(red[0], red[1]), fmaxf(red[2], red[3]));
  float e[8];
  float sum = 0.f;
  if (act) {
#pragma unroll
    for (int k = 0; k < 8; ++k) { e[k] = __expf(v[k] - m); sum += e[k]; }
  }
#pragma unroll
  for (int off = 32; off > 0; off >>= 1) sum += __shfl_down(sum, off, 64);
  if (lane == 0) red[4 + wid] = sum;
  __syncthreads();
  sum = red[4] + red[5] + red[6] + red[7];
  const float inv = 1.0f / sum;
  if (act) {
    ushort4 o0, o1;
    o0.x = f2bf(e[0] * inv); o0.y = f2bf(e[1] * inv);
    o0.z = f2bf(e[2] * inv); o0.w = f2bf(e[3] * inv);
    o1.x = f2bf(e[4] * inv); o1.y = f2bf(e[5] * inv);
    o1.z = f2bf(e[6] * inv); o1.w = f2bf(e[7] * inv);
    ushort4* dst = (ushort4*)(bb + (long)bn * T256 + (long)cl * 2);
    dst[0] = o0;
    dst[1] = o1;
  }
}

// ---------------- PV: 128x128 m97 core over compact attn --------------------
__global__ __launch_bounds__(256) void gemm_pv(
    const char* __restrict__ attn, const unsigned short* __restrict__ VtB,
    float* __restrict__ Out) {
  const int bz = blockIdx.z;
  const int bm = blockIdx.x, bn = blockIdx.y;
  const int R = bm >> 1;               // 256-tile row
  const char* Ab = attn + (long)bz * BATCH256 + (long)(R * (R + 1) / 2) * T256;
  const unsigned short* B = VtB + (long)bz * SS * HH;

  __shared__ unsigned short As[128 * 32];
  __shared__ unsigned short Bs[128 * 32];

  const int tid = threadIdx.x;
  const int wave = tid >> 6;
  const int lane = tid & 63;
  const int wr = wave >> 1, wc = wave & 1;
  const int lr = lane >> 4, lc = lane & 15;

  f32x4 acc[4][4];
  const f32x4 z4 = {0.f, 0.f, 0.f, 0.f};
#pragma unroll
  for (int i = 0; i < 4; ++i)
#pragma unroll
    for (int j = 0; j < 4; ++j) acc[i][j] = z4;

  const int r0 = tid >> 2;
  const int c8 = (tid & 3) * 8;
  const char* aP0 = Ab + (long)((bm & 1) * 128 + r0) * 1024 + c8 * 2;
  const char* aP1 = Ab + (long)((bm & 1) * 128 + r0 + 64) * 1024 + c8 * 2;
  const unsigned short* bS0 = B + (long)(bn * 128 + r0) * SS + c8;
  const unsigned short* bS1 = B + (long)(bn * 128 + r0 + 64) * SS + c8;
  char* asL0 = (char*)As + wave * 1024;
  char* asL1 = (char*)As + 4096 + wave * 1024;
  char* bsL0 = (char*)Bs + wave * 1024;
  char* bsL1 = (char*)Bs + 4096 + wave * 1024;

  const int kTiles = (R + 1) * 8;
  for (int kt = 0; kt < kTiles; ++kt) {
    const int ko = kt * 32;
    const long offA = (long)(ko >> 8) * T256 + ((ko & 255) << 1);
    __syncthreads();
    gl_lds16(aP0 + offA, asL0);
    gl_lds16(aP1 + offA, asL1);
    gl_lds16((const void*)(bS0 + ko), bsL0);
    gl_lds16((const void*)(bS1 + ko), bsL1);
    __syncthreads();
    bf16x8 af[4], bg[4];
#pragma unroll
    for (int i = 0; i < 4; ++i)
      af[i] = *(const bf16x8*)(const void*)&As[(wr * 64 + i * 16 + lc) * 32 + lr * 8];
#pragma unroll
    for (int j = 0; j < 4; ++j)
      bg[j] = *(const bf16x8*)(const void*)&Bs[(wc * 64 + j * 16 + lc) * 32 + lr * 8];
#pragma unroll
    for (int i = 0; i < 4; ++i)
#pragma unroll
      for (int j = 0; j < 4; ++j)
        acc[i][j] = __builtin_amdgcn_mfma_f32_16x16x32_bf16(af[i], bg[j],
                                                            acc[i][j], 0, 0, 0);
  }

#pragma unroll
  for (int i = 0; i < 4; ++i)
#pragma unroll
    for (int j = 0; j < 4; ++j)
#pragma unroll
      for (int r = 0; r < 4; ++r) {
        const int row = bm * 128 + wr * 64 + i * 16 + lr * 4 + r;
        const int col = bn * 128 + wc * 64 + j * 16 + lc;
        Out[((long)bz * SS + row) * HH + col] = acc[i][j][r];
      }
}

extern "C" void kernel_launch(void* const* d_in, const int* in_sizes, int n_in,
                              void* d_out, int out_size, void* d_ws, size_t ws_size,
                              hipStream_t stream) {
  (void)in_sizes; (void)n_in; (void)out_size; (void)ws_size;
  const float* x = (const float*)d_in[0];
  const unsigned char* mask_raw = (const unsigned char*)d_in[1];
  const float* Wq = (const float*)d_in[2];
  const float* bq = (const float*)d_in[3];
  const float* Wk = (const float*)d_in[4];
  const float* bk = (const float*)d_in[5];
  const float* Wv = (const float*)d_in[6];
  const float* bv = (const float*)d_in[7];
  char* ws = (char*)d_ws;

  unsigned short* Xbf = (unsigned short*)(ws + OFF_XBF);
  unsigned short* Wbf = (unsigned short*)(ws + OFF_WBF);
  unsigned short* Qb = (unsigned short*)(ws + OFF_Q);
  unsigned short* Kb = (unsigned short*)(ws + OFF_K);
  unsigned short* Vb = (unsigned short*)(ws + OFF_V);
  unsigned short* Vt = (unsigned short*)(ws + OFF_VT);
  unsigned char* mask = (unsigned char*)(ws + OFF_MASK);
  float* meanV = (float*)(ws + OFF_MEANV);

  const long MS = (long)BB * SS;  // 16384

  // allow 128 KiB dynamic LDS for gemm256
  (void)hipFuncSetAttribute((const void*)gemm256<0>,
                            hipFuncAttributeMaxDynamicSharedMemorySize, 131072);
  (void)hipFuncSetAttribute((const void*)gemm256<1>,
                            hipFuncAttributeMaxDynamicSharedMemorySize, 131072);

  // 0. canonicalize mask
  canon_mask<<<1, 256, 0, stream>>>(mask_raw, mask, (int)(BB * SS));

  // 1. fp32 -> bf16
  cvt_f32_bf16<<<2048, 256, 0, stream>>>(x, Xbf, (int)(MS * HH / 4));
  cvt_f32_bf16<<<256, 256, 0, stream>>>(Wq, Wbf, HH * HH / 4);
  cvt_f32_bf16<<<256, 256, 0, stream>>>(Wk, Wbf + HH * HH, HH * HH / 4);
  cvt_f32_bf16<<<256, 256, 0, stream>>>(Wv, Wbf + 2 * HH * HH, HH * HH / 4);

  // 2. fused QKV projection (256^2 swizzled core): grid (64,4,3)
  gemm256<0><<<dim3(MS / 256, HH / 256, 3), 512, 131072, stream>>>(
      Xbf, 0, Wbf, (long)HH * HH,
      (char*)Qb, (char*)Kb, (char*)Vb, bq, bk, bv, nullptr, nullptr);

  // 3. V -> Vt ; column sums for masked-row fixup
  transpose_v<<<dim3(HH / 32, SS / 32, BB), dim3(32, 8), 0, stream>>>(Vb, Vt);
  meanv_sum<<<dim3(HH / 4, BB), 256, 0, stream>>>(Vt, meanV);

  // 4. scores: triangular 256^2 tiles, all batches: grid (36,1,8)
  gemm256<1><<<dim3(NTRI256, 1, BB), 512, 131072, stream>>>(
      Qb, (long)SS * HH, Kb, (long)SS * HH,
      nullptr, nullptr, nullptr, nullptr, nullptr, nullptr,
      mask, ws + OFF_SCORES);

  // 5. softmax over causal prefix, in-place -> compact bf16
  softmax_tri<<<dim3(SS, BB), 256, 0, stream>>>(ws + OFF_SCORES);

  // 6. out = attn @ V (compact A, causal K-limit)
  gemm_pv<<<dim3(SS / 128, HH / 128, BB), 256, 0, stream>>>(
      ws + OFF_SCORES, Vt, (float*)d_out);

  // 7. masked query rows -> uniform mean of V
  fixup_masked<<<BB * SS, 256, 0, stream>>>((float*)d_out, mask, meanV);
}

// Round 6
// 373.687 us; speedup vs baseline: 1.2039x; 1.1198x over previous
//
#include <hip/hip_runtime.h>
#include <stdint.h>

typedef __bf16 bf16x8 __attribute__((ext_vector_type(8)));
typedef float f32x4 __attribute__((ext_vector_type(4)));

#define BB 8
#define SS 2048
#define HH 1024

// compact triangular scores: 128x128 tiles (r3-proven layout).
// row slot 512B fp32 / first 256B bf16 after softmax. 16x16 grid -> 136 tiles.
#define TILE_B   65536ll
#define NTRI     136
#define BATCH_B  (NTRI * TILE_B)   // 8,912,896 B per batch

// ws layout (bytes). Peak ~169 MiB (validated r3-r5).
#define OFF_Q      0ll
#define OFF_K      33554432ll
#define OFF_VT     67108864ll
#define OFF_MASK   100663296ll
#define OFF_MEANV  100679680ll
#define OFF_TMP    101711872ll
#define OFF_XBF    (OFF_TMP)
#define OFF_WBF    (OFF_TMP + 33554432ll)
#define OFF_V      (OFF_TMP + 39845888ll)
#define OFF_SCORES (OFF_TMP)

__device__ __forceinline__ unsigned short f2bf(float f) {
  unsigned int u = __float_as_uint(f);
  u += 0x7FFFu + ((u >> 16) & 1u);   // RTNE
  return (unsigned short)(u >> 16);
}
__device__ __forceinline__ float bf2f(unsigned short u) {
  return __uint_as_float(((unsigned int)u) << 16);
}

__device__ __forceinline__ void gl_lds16(const void* g, void* l) {
  __builtin_amdgcn_global_load_lds(
      (const __attribute__((address_space(1))) void*)g,
      (__attribute__((address_space(3))) void*)l, 16, 0, 0);
}

// ---------------- mask canonicalizer (uint8 / int32 / float32) --------------
__global__ void canon_mask(const unsigned char* __restrict__ m,
                           unsigned char* __restrict__ out, int n) {
  __shared__ int cnt[4];
  const int t = threadIdx.x;
  if (t < 4) cnt[t] = 0;
  __syncthreads();
  int loc[4] = {0, 0, 0, 0};
  for (int i = t; i < n; i += 256)
    if (m[i] != 0) loc[i & 3]++;
  for (int r = 0; r < 4; ++r)
    if (loc[r]) atomicAdd(&cnt[r], loc[r]);
  __syncthreads();
  const int c0 = cnt[0], c1 = cnt[1], c2 = cnt[2], c3 = cnt[3];
  if (c0 > 0 && c1 == 0 && c2 == 0 && c3 == 0) {        // int32 0/1
    const int* mi = (const int*)m;
    for (int i = t; i < n; i += 256) out[i] = mi[i] ? 1 : 0;
  } else if (c0 == 0 && (c2 > 0 || c3 > 0)) {           // float32
    const float* mf = (const float*)m;
    for (int i = t; i < n; i += 256) out[i] = (mf[i] != 0.0f) ? 1 : 0;
  } else {                                              // uint8 bool
    for (int i = t; i < n; i += 256) out[i] = m[i] ? 1 : 0;
  }
}

__global__ void cvt_f32_bf16(const float* __restrict__ in,
                             unsigned short* __restrict__ out, int n4) {
  int i = blockIdx.x * blockDim.x + threadIdx.x;
  int stride = gridDim.x * blockDim.x;
  for (; i < n4; i += stride) {
    float4 v = ((const float4*)in)[i];
    ushort4 o;
    o.x = f2bf(v.x); o.y = f2bf(v.y); o.z = f2bf(v.z); o.w = f2bf(v.w);
    ((ushort4*)out)[i] = o;
  }
}

// 3 weight matrices in one dispatch (blockIdx.y picks src)
__global__ void cvt_w3(const float* __restrict__ Wq, const float* __restrict__ Wk,
                       const float* __restrict__ Wv, unsigned short* __restrict__ out) {
  const int z = blockIdx.y;
  const float* src = (z == 0) ? Wq : (z == 1) ? Wk : Wv;
  unsigned short* dst = out + (long)z * (HH * HH);
  const int n4 = HH * HH / 4;
  int i = blockIdx.x * 256 + threadIdx.x;
  for (; i < n4; i += 256 * 256) {
    float4 v = ((const float4*)src)[i];
    ushort4 o;
    o.x = f2bf(v.x); o.y = f2bf(v.y); o.z = f2bf(v.z); o.w = f2bf(v.w);
    ((ushort4*)dst)[i] = o;
  }
}

// V [S,H] -> Vt [H,S] per batch, 64x64 tiles, vectorized
__global__ __launch_bounds__(256) void transpose_v(
    const unsigned short* __restrict__ V, unsigned short* __restrict__ Vt) {
  __shared__ unsigned short t[64][66];
  const int b = blockIdx.z;
  const unsigned short* Vb = V + (size_t)b * SS * HH;
  unsigned short* Vtb = Vt + (size_t)b * SS * HH;
  const int x0 = blockIdx.x * 64;   // h
  const int y0 = blockIdx.y * 64;   // s
  const int tid = threadIdx.x;
  const int lr = tid >> 4;          // 0..15
  const int lc = (tid & 15) * 4;    // 0..60
#pragma unroll
  for (int i = 0; i < 4; ++i) {
    const int row = i * 16 + lr;
    *(ushort4*)&t[row][lc] =
        *(const ushort4*)(Vb + (size_t)(y0 + row) * HH + x0 + lc);
  }
  __syncthreads();
#pragma unroll
  for (int i = 0; i < 4; ++i) {
    const int c = i * 16 + lr;      // out row (h)
    ushort4 o;
    o.x = t[lc + 0][c]; o.y = t[lc + 1][c];
    o.z = t[lc + 2][c]; o.w = t[lc + 3][c];
    *(ushort4*)(Vtb + (size_t)(x0 + c) * SS + y0 + lc) = o;
  }
}

__global__ __launch_bounds__(256) void meanv_sum(
    const unsigned short* __restrict__ Vt, float* __restrict__ out) {
  const int b = blockIdx.y;
  const int wave = threadIdx.x >> 6, lane = threadIdx.x & 63;
  const int h = blockIdx.x * 4 + wave;
  const unsigned short* row = Vt + ((long)b * HH + h) * SS;
  float s = 0.f;
#pragma unroll
  for (int j = 0; j < 4; ++j) {
    const ushort4* p = (const ushort4*)(row + j * 512 + lane * 8);
    ushort4 u0 = p[0], u1 = p[1];
    s += bf2f(u0.x) + bf2f(u0.y) + bf2f(u0.z) + bf2f(u0.w)
       + bf2f(u1.x) + bf2f(u1.y) + bf2f(u1.z) + bf2f(u1.w);
  }
#pragma unroll
  for (int off = 32; off > 0; off >>= 1) s += __shfl_down(s, off, 64);
  if (lane == 0) out[(long)b * HH + h] = s;
}

__global__ __launch_bounds__(256) void fixup_masked(
    float* __restrict__ out, const unsigned char* __restrict__ mask,
    const float* __restrict__ sums) {
  const long row = blockIdx.x;
  if (mask[row]) return;
  const long b = row >> 11;
  const int t = threadIdx.x;
  float4 v = ((const float4*)(sums + b * HH))[t];
  v.x *= (1.f / 2048.f); v.y *= (1.f / 2048.f);
  v.z *= (1.f / 2048.f); v.w *= (1.f / 2048.f);
  ((float4*)(out + row * HH))[t] = v;
}

// ---------------- 256x256 fused QKV (ring-4, swizzled, counted vmcnt) -------
// grid (64,4,3) = 768 blocks = 3.0 exact rounds. Epilogue: XOR-swizzled LDS
// bounce (conflict-free b16 writes) -> full-line coalesced global stores.
__global__ __launch_bounds__(512, 2) void gemm256(
    const unsigned short* __restrict__ Abase,
    const unsigned short* __restrict__ Bbase, long bStride,
    char* __restrict__ Cq, char* __restrict__ Ck, char* __restrict__ Cv,
    const float* __restrict__ biasq, const float* __restrict__ biask,
    const float* __restrict__ biasv) {
  extern __shared__ char smem[];
  const int tid = threadIdx.x;
  const int wave = tid >> 6, lane = tid & 63;
  const int wr = wave >> 2, wc = wave & 3;
  const int l15 = lane & 15, l4 = lane >> 4;
  const int bz = blockIdx.z;
  const int bm = blockIdx.x, bn = blockIdx.y;

  const unsigned short* A = Abase;
  const unsigned short* B = Bbase + (long)bz * bStride;

  // inverse-swizzled staging source (linear LDS dest slot s = tid)
  const int s = tid;
  const int rA = ((s >> 3) << 1) | (((s >> 2) & 1) ^ ((s >> 4) & 1));
  const int cA = (s & 3) ^ (rA & 3);
  const char* aS0 = (const char*)A + (long)(bm * 256 + rA) * 2048 + cA * 16;
  const char* aS1 = (const char*)A + (long)(bm * 256 + 128 + rA) * 2048 + cA * 16;
  const char* bS0 = (const char*)B + (long)(bn * 256 + rA) * 2048 + cA * 16;
  const char* bS1 = (const char*)B + (long)(bn * 256 + 128 + rA) * 2048 + cA * 16;
  const int ldsW = wave << 10;

#define STAGE256(t_) do { \
    char* _p = smem + (((t_) & 3) << 15); \
    const long _ko = (long)(t_) << 6; \
    gl_lds16(aS0 + _ko, _p + ldsW); \
    gl_lds16(aS1 + _ko, _p + 8192 + ldsW); \
    gl_lds16(bS0 + _ko, _p + 16384 + ldsW); \
    gl_lds16(bS1 + _ko, _p + 24576 + ldsW); } while (0)

  const int baseSwz = ((l15 * 64 + (l4 << 4)) ^ ((l15 & 7) << 4));
  const int rdA = (wr << 13) + baseSwz;
  const int rdB = 16384 + (wc << 12) + baseSwz;

  f32x4 acc[8][4];
  const f32x4 z4 = {0.f, 0.f, 0.f, 0.f};
#pragma unroll
  for (int m = 0; m < 8; ++m)
#pragma unroll
    for (int n = 0; n < 4; ++n) acc[m][n] = z4;

  STAGE256(0); STAGE256(1); STAGE256(2);
  asm volatile("s_waitcnt vmcnt(8)" ::: "memory");
  __builtin_amdgcn_s_barrier();
  __builtin_amdgcn_sched_barrier(0);

  for (int t = 0; t < 32; ++t) {
    if (t < 29) STAGE256(t + 3);
    const char* bufp = smem + ((t & 3) << 15);
    bf16x8 af[8], bg[4];
#pragma unroll
    for (int m = 0; m < 8; ++m)
      af[m] = *(const bf16x8*)(bufp + rdA + (m << 10));
#pragma unroll
    for (int n = 0; n < 4; ++n)
      bg[n] = *(const bf16x8*)(bufp + rdB + (n << 10));
    __builtin_amdgcn_s_setprio(1);
#pragma unroll
    for (int m = 0; m < 8; ++m)
#pragma unroll
      for (int n = 0; n < 4; ++n)
        acc[m][n] = __builtin_amdgcn_mfma_f32_16x16x32_bf16(af[m], bg[n],
                                                            acc[m][n], 0, 0, 0);
    __builtin_amdgcn_s_setprio(0);
    __builtin_amdgcn_sched_barrier(0);
    if (t < 29)       asm volatile("s_waitcnt vmcnt(8)" ::: "memory");
    else if (t == 29) asm volatile("s_waitcnt vmcnt(4)" ::: "memory");
    else if (t == 30) asm volatile("s_waitcnt vmcnt(0)" ::: "memory");
    if (t < 31) {
      __builtin_amdgcn_s_barrier();
      __builtin_amdgcn_sched_barrier(0);
      asm volatile("" ::: "memory");
    }
  }
#undef STAGE256

  const int rl0 = (wr << 7) + (l4 << 2);
  const int cl0 = (wc << 6) + l15;
  const float* bias = (bz == 0) ? biasq : (bz == 1) ? biask : biasv;
  unsigned short* C = (unsigned short*)((bz == 0) ? Cq : (bz == 1) ? Ck : Cv);
  __syncthreads();
  // acc -> LDS bf16 [256][256], col XOR'd by l4 (conflict-free writes)
#pragma unroll
  for (int n = 0; n < 4; ++n) {
    const int cl = cl0 + n * 16;
    const float bv = bias[bn * 256 + cl];
    const int colx = cl ^ (l4 << 4);
#pragma unroll
    for (int m = 0; m < 8; ++m) {
      const int rl = rl0 + m * 16;
#pragma unroll
      for (int r = 0; r < 4; ++r)
        *(unsigned short*)(smem + (rl + r) * 512 + colx * 2) =
            f2bf(acc[m][n][r] + bv);
    }
  }
  __syncthreads();
  const long rowg0 = (long)bm * 256;
  const long colb0 = (long)bn * 512;
#pragma unroll
  for (int i = 0; i < 16; ++i) {
    const int s2 = i * 512 + tid;
    const int row = s2 >> 5;
    const int cb = s2 & 31;
    const int lb = (row * 512 + (cb << 4)) ^ (((row >> 2) & 3) << 5);
    *(uint4*)((char*)C + (rowg0 + row) * 2048 + colb0 + (cb << 4)) =
        *(const uint4*)(smem + lb);
  }
}

// -------- 128x128 ring-4 swizzled core: SCORES (triangular, 2 blocks/CU) ----
__global__ __launch_bounds__(256, 2) void gemm128s(
    const unsigned short* __restrict__ Qb, const unsigned short* __restrict__ Kb,
    char* __restrict__ scoresBase, const unsigned char* __restrict__ maskg) {
  __shared__ __align__(16) char smem[65536];
  const int tid = threadIdx.x;
  const int wave = tid >> 6, lane = tid & 63;
  const int wr = wave >> 1, wc = wave & 1;
  const int l15 = lane & 15, l4 = lane >> 4;
  const int bz = blockIdx.y;

  int t0 = blockIdx.x, bm = 0, a_ = 0;
  while (a_ + bm + 1 <= t0) { ++bm; a_ += bm; }
  const int bn = t0 - a_;

  const unsigned short* A = Qb + (long)bz * SS * HH;
  const unsigned short* B = Kb + (long)bz * SS * HH;

  // 2 slots/thread per 8KB chunk-half (s = tid, tid+256), inverse-swizzled src
  const int s0 = tid, s1 = tid + 256;
  const int rA0 = ((s0 >> 3) << 1) | (((s0 >> 2) & 1) ^ ((s0 >> 4) & 1));
  const int cA0 = (s0 & 3) ^ (rA0 & 3);
  const int rA1 = ((s1 >> 3) << 1) | (((s1 >> 2) & 1) ^ ((s1 >> 4) & 1));
  const int cA1 = (s1 & 3) ^ (rA1 & 3);
  const char* aG0 = (const char*)A + (long)(bm * 128 + rA0) * 2048 + cA0 * 16;
  const char* aG1 = (const char*)A + (long)(bm * 128 + rA1) * 2048 + cA1 * 16;
  const char* bG0 = (const char*)B + (long)(bn * 128 + rA0) * 2048 + cA0 * 16;
  const char* bG1 = (const char*)B + (long)(bn * 128 + rA1) * 2048 + cA1 * 16;
  const int ldsL0 = wave << 10;
  const int ldsL1 = 4096 + (wave << 10);

#define STG(t_) do { \
    char* _p = smem + (((t_) & 3) << 14); \
    const long _ko = (long)(t_) << 6; \
    gl_lds16(aG0 + _ko, _p + ldsL0); \
    gl_lds16(aG1 + _ko, _p + ldsL1); \
    gl_lds16(bG0 + _ko, _p + 8192 + ldsL0); \
    gl_lds16(bG1 + _ko, _p + 8192 + ldsL1); } while (0)

  const int baseSwz = ((l15 * 64 + (l4 << 4)) ^ ((l15 & 7) << 4));
  const int rdA = (wr << 12) + baseSwz;
  const int rdB = 8192 + (wc << 12) + baseSwz;

  f32x4 acc[4][4];
  const f32x4 z4 = {0.f, 0.f, 0.f, 0.f};
#pragma unroll
  for (int m = 0; m < 4; ++m)
#pragma unroll
    for (int n = 0; n < 4; ++n) acc[m][n] = z4;

  STG(0); STG(1); STG(2);
  asm volatile("s_waitcnt vmcnt(8)" ::: "memory");
  __builtin_amdgcn_s_barrier();
  __builtin_amdgcn_sched_barrier(0);

  const int kT = 32;
  for (int t = 0; t < kT; ++t) {
    if (t + 3 < kT) STG(t + 3);
    const char* bufp = smem + ((t & 3) << 14);
    bf16x8 af[4], bg[4];
#pragma unroll
    for (int m = 0; m < 4; ++m)
      af[m] = *(const bf16x8*)(bufp + rdA + (m << 10));
#pragma unroll
    for (int n = 0; n < 4; ++n)
      bg[n] = *(const bf16x8*)(bufp + rdB + (n << 10));
    __builtin_amdgcn_s_setprio(1);
#pragma unroll
    for (int m = 0; m < 4; ++m)
#pragma unroll
      for (int n = 0; n < 4; ++n)
        acc[m][n] = __builtin_amdgcn_mfma_f32_16x16x32_bf16(af[m], bg[n],
                                                            acc[m][n], 0, 0, 0);
    __builtin_amdgcn_s_setprio(0);
    __builtin_amdgcn_sched_barrier(0);
    if (t + 3 < kT)       asm volatile("s_waitcnt vmcnt(8)" ::: "memory");
    else if (t + 3 == kT) asm volatile("s_waitcnt vmcnt(4)" ::: "memory");
    else if (t + 2 == kT) asm volatile("s_waitcnt vmcnt(0)" ::: "memory");
    if (t + 1 < kT) {
      __builtin_amdgcn_s_barrier();
      __builtin_amdgcn_sched_barrier(0);
      asm volatile("" ::: "memory");
    }
  }
#undef STG

  // epilogue: masked fp32 compact write via XOR-swizzled LDS bounce
  const int rl0 = (wr << 6) + (l4 << 2);
  const int cl0 = (wc << 6) + l15;
  char* Ct = scoresBase + (long)bz * BATCH_B + (long)t0 * TILE_B;
  const unsigned char* mrow = maskg + (long)bz * SS;
  bool km[4]; int kg[4];
#pragma unroll
  for (int n = 0; n < 4; ++n) {
    kg[n] = bn * 128 + cl0 + n * 16;
    km[n] = mrow[kg[n]] != 0;
  }
  __syncthreads();
#pragma unroll
  for (int m = 0; m < 4; ++m)
#pragma unroll
    for (int r = 0; r < 4; ++r) {
      const int ql = rl0 + m * 16 + r;
      const int q = bm * 128 + ql;
      const bool qm = mrow[q] != 0;
#pragma unroll
      for (int n = 0; n < 4; ++n) {
        float v;
        if (!qm) v = 0.0f;             // fixup overwrites these out rows
        else if (kg[n] <= q && km[n]) v = acc[m][n][r] * 0.03125f;
        else v = -1.0e9f;
        const int colx = (cl0 + n * 16) ^ (l4 << 4);
        *(float*)(smem + ql * 512 + colx * 4) = v;
      }
    }
  __syncthreads();
#pragma unroll
  for (int i = 0; i < 16; ++i) {
    const int s2 = i * 256 + tid;
    const int row = s2 >> 5;
    const int cb = s2 & 31;
    const int lb = (row * 512 + (cb << 4)) ^ (((row >> 2) & 3) << 6);
    *(uint4*)(Ct + (long)row * 512 + (cb << 4)) = *(const uint4*)(smem + lb);
  }
}

// ---------------- softmax over causal prefix, compact 128-tiles (r3) --------
__global__ __launch_bounds__(256) void softmax_tri(char* __restrict__ base) {
  const int r = blockIdx.x;
  const int bz = blockIdx.y;
  const int bm = r >> 7;
  const int w = (bm + 1) << 7;
  char* bb = base + (long)bz * BATCH_B +
             (long)(bm * (bm + 1) / 2) * TILE_B + (long)(r & 127) * 512;
  const int t = threadIdx.x;
  const bool act = (t << 3) < w;
  const int bn = t >> 4;
  const int cl = (t << 3) & 127;
  const char* src = bb + (long)bn * TILE_B + (long)cl * 4;
  float v[8];
  float m = -3.0e38f;
  if (act) {
    float4 a = ((const float4*)src)[0];
    float4 b2 = ((const float4*)src)[1];
    v[0] = a.x; v[1] = a.y; v[2] = a.z; v[3] = a.w;
    v[4] = b2.x; v[5] = b2.y; v[6] = b2.z; v[7] = b2.w;
#pragma unroll
    for (int k = 0; k < 8; ++k) m = fmaxf(m, v[k]);
  }
  __shared__ float red[8];
#pragma unroll
  for (int off = 32; off > 0; off >>= 1) m = fmaxf(m, __shfl_down(m, off, 64));
  const int wid = t >> 6, lane = t & 63;
  if (lane == 0) red[wid] = m;
  __syncthreads();
  m = fmaxf(fmaxf(red[0], red[1]), fmaxf(red[2], red[3]));
  float e[8];
  float s = 0.f;
  if (act) {
#pragma unroll
    for (int k = 0; k < 8; ++k) { e[k] = __expf(v[k] - m); s += e[k]; }
  }
#pragma unroll
  for (int off = 32; off > 0; off >>= 1) s += __shfl_down(s, off, 64);
  if (lane == 0) red[4 + wid] = s;
  __syncthreads();
  s = red[4] + red[5] + red[6] + red[7];
  const float inv = 1.0f / s;
  if (act) {
    ushort4 o0, o1;
    o0.x = f2bf(e[0] * inv); o0.y = f2bf(e[1] * inv);
    o0.z = f2bf(e[2] * inv); o0.w = f2bf(e[3] * inv);
    o1.x = f2bf(e[4] * inv); o1.y = f2bf(e[5] * inv);
    o1.z = f2bf(e[6] * inv); o1.w = f2bf(e[7] * inv);
    ushort4* dst = (ushort4*)(bb + (long)bn * TILE_B + (long)cl * 2);
    dst[0] = o0;
    dst[1] = o1;
  }
}

// -------- 128x128 ring-4 swizzled core: PV (causal K-limit, 2 blocks/CU) ----
__global__ __launch_bounds__(256, 2) void gemm_pv(
    const char* __restrict__ attn, const unsigned short* __restrict__ VtB,
    float* __restrict__ Out) {
  __shared__ __align__(16) char smem[65536];
  const int tid = threadIdx.x;
  const int wave = tid >> 6, lane = tid & 63;
  const int wr = wave >> 1, wc = wave & 1;
  const int l15 = lane & 15, l4 = lane >> 4;
  const int bz = blockIdx.z;
  const int bm = 15 - blockIdx.x;      // longest-first for packing
  const int bn = blockIdx.y;

  const char* Ab = attn + (long)bz * BATCH_B + (long)(bm * (bm + 1) / 2) * TILE_B;
  const unsigned short* B = VtB + (long)bz * SS * HH;

  const int s0 = tid, s1 = tid + 256;
  const int rA0 = ((s0 >> 3) << 1) | (((s0 >> 2) & 1) ^ ((s0 >> 4) & 1));
  const int cA0 = (s0 & 3) ^ (rA0 & 3);
  const int rA1 = ((s1 >> 3) << 1) | (((s1 >> 2) & 1) ^ ((s1 >> 4) & 1));
  const int cA1 = (s1 & 3) ^ (rA1 & 3);
  // A: compact bf16 tiles, row slot 512B (256B valid); tile jump every 4 chunks
  const char* aB0 = Ab + (long)rA0 * 512 + cA0 * 16;
  const char* aB1 = Ab + (long)rA1 * 512 + cA1 * 16;
  const char* bG0 = (const char*)(B + (long)(bn * 128 + rA0) * SS) + cA0 * 16;
  const char* bG1 = (const char*)(B + (long)(bn * 128 + rA1) * SS) + cA1 * 16;
  const int ldsL0 = wave << 10;
  const int ldsL1 = 4096 + (wave << 10);

#define STGPV(t_) do { \
    char* _p = smem + (((t_) & 3) << 14); \
    const long _aO = (long)((t_) >> 2) * TILE_B + (long)((t_) & 3) * 64; \
    const long _bO = (long)(t_) << 6; \
    gl_lds16(aB0 + _aO, _p + ldsL0); \
    gl_lds16(aB1 + _aO, _p + ldsL1); \
    gl_lds16(bG0 + _bO, _p + 8192 + ldsL0); \
    gl_lds16(bG1 + _bO, _p + 8192 + ldsL1); } while (0)

  const int baseSwz = ((l15 * 64 + (l4 << 4)) ^ ((l15 & 7) << 4));
  const int rdA = (wr << 12) + baseSwz;
  const int rdB = 8192 + (wc << 12) + baseSwz;

  f32x4 acc[4][4];
  const f32x4 z4 = {0.f, 0.f, 0.f, 0.f};
#pragma unroll
  for (int m = 0; m < 4; ++m)
#pragma unroll
    for (int n = 0; n < 4; ++n) acc[m][n] = z4;

  STGPV(0); STGPV(1); STGPV(2);
  asm volatile("s_waitcnt vmcnt(8)" ::: "memory");
  __builtin_amdgcn_s_barrier();
  __builtin_amdgcn_sched_barrier(0);

  const int kT = (bm + 1) * 4;         // causal K-chunks (min 4)
  for (int t = 0; t < kT; ++t) {
    if (t + 3 < kT) STGPV(t + 3);
    const char* bufp = smem + ((t & 3) << 14);
    bf16x8 af[4], bg[4];
#pragma unroll
    for (int m = 0; m < 4; ++m)
      af[m] = *(const bf16x8*)(bufp + rdA + (m << 10));
#pragma unroll
    for (int n = 0; n < 4; ++n)
      bg[n] = *(const bf16x8*)(bufp + rdB + (n << 10));
    __builtin_amdgcn_s_setprio(1);
#pragma unroll
    for (int m = 0; m < 4; ++m)
#pragma unroll
      for (int n = 0; n < 4; ++n)
        acc[m][n] = __builtin_amdgcn_mfma_f32_16x16x32_bf16(af[m], bg[n],
                                                            acc[m][n], 0, 0, 0);
    __builtin_amdgcn_s_setprio(0);
    __builtin_amdgcn_sched_barrier(0);
    if (t + 3 < kT)       asm volatile("s_waitcnt vmcnt(8)" ::: "memory");
    else if (t + 3 == kT) asm volatile("s_waitcnt vmcnt(4)" ::: "memory");
    else if (t + 2 == kT) asm volatile("s_waitcnt vmcnt(0)" ::: "memory");
    if (t + 1 < kT) {
      __builtin_amdgcn_s_barrier();
      __builtin_amdgcn_sched_barrier(0);
      asm volatile("" ::: "memory");
    }
  }
#undef STGPV

  // epilogue: fp32 out via XOR-swizzled LDS bounce, full 512B-line writes
  const int rl0 = (wr << 6) + (l4 << 2);
  const int cl0 = (wc << 6) + l15;
  __syncthreads();
#pragma unroll
  for (int m = 0; m < 4; ++m)
#pragma unroll
    for (int r = 0; r < 4; ++r) {
      const int ql = rl0 + m * 16 + r;
#pragma unroll
      for (int n = 0; n < 4; ++n) {
        const int colx = (cl0 + n * 16) ^ (l4 << 4);
        *(float*)(smem + ql * 512 + colx * 4) = acc[m][n][r];
      }
    }
  __syncthreads();
  char* Ob = (char*)(Out + ((long)bz * SS + bm * 128) * HH + bn * 128);
#pragma unroll
  for (int i = 0; i < 16; ++i) {
    const int s2 = i * 256 + tid;
    const int row = s2 >> 5;
    const int cb = s2 & 31;
    const int lb = (row * 512 + (cb << 4)) ^ (((row >> 2) & 3) << 6);
    *(uint4*)(Ob + (long)row * 4096 + (cb << 4)) = *(const uint4*)(smem + lb);
  }
}

extern "C" void kernel_launch(void* const* d_in, const int* in_sizes, int n_in,
                              void* d_out, int out_size, void* d_ws, size_t ws_size,
                              hipStream_t stream) {
  (void)in_sizes; (void)n_in; (void)out_size; (void)ws_size;
  const float* x = (const float*)d_in[0];
  const unsigned char* mask_raw = (const unsigned char*)d_in[1];
  const float* Wq = (const float*)d_in[2];
  const float* bq = (const float*)d_in[3];
  const float* Wk = (const float*)d_in[4];
  const float* bk = (const float*)d_in[5];
  const float* Wv = (const float*)d_in[6];
  const float* bv = (const float*)d_in[7];
  char* ws = (char*)d_ws;

  unsigned short* Xbf = (unsigned short*)(ws + OFF_XBF);
  unsigned short* Wbf = (unsigned short*)(ws + OFF_WBF);
  unsigned short* Qb = (unsigned short*)(ws + OFF_Q);
  unsigned short* Kb = (unsigned short*)(ws + OFF_K);
  unsigned short* Vb = (unsigned short*)(ws + OFF_V);
  unsigned short* Vt = (unsigned short*)(ws + OFF_VT);
  unsigned char* mask = (unsigned char*)(ws + OFF_MASK);
  float* meanV = (float*)(ws + OFF_MEANV);

  const long MS = (long)BB * SS;  // 16384

  (void)hipFuncSetAttribute((const void*)gemm256,
                            hipFuncAttributeMaxDynamicSharedMemorySize, 131072);

  // 0. canonicalize mask
  canon_mask<<<1, 256, 0, stream>>>(mask_raw, mask, (int)(BB * SS));

  // 1. fp32 -> bf16
  cvt_f32_bf16<<<2048, 256, 0, stream>>>(x, Xbf, (int)(MS * HH / 4));
  cvt_w3<<<dim3(256, 3), 256, 0, stream>>>(Wq, Wk, Wv, Wbf);

  // 2. fused QKV projection (256^2 swizzled core): grid (64,4,3) = 3.0 rounds
  gemm256<<<dim3(MS / 256, HH / 256, 3), 512, 131072, stream>>>(
      Xbf, Wbf, (long)HH * HH,
      (char*)Qb, (char*)Kb, (char*)Vb, bq, bk, bv);

  // 3. V -> Vt ; column sums for masked-row fixup
  transpose_v<<<dim3(HH / 64, SS / 64, BB), 256, 0, stream>>>(Vb, Vt);
  meanv_sum<<<dim3(HH / 4, BB), 256, 0, stream>>>(Vt, meanV);

  // 4. scores: 128^2 triangular tiles, 2 blocks/CU: grid (136,8) = 1088
  gemm128s<<<dim3(NTRI, BB), 256, 0, stream>>>(
      Qb, Kb, ws + OFF_SCORES, mask);

  // 5. softmax over causal prefix, in-place -> compact bf16
  softmax_tri<<<dim3(SS, BB), 256, 0, stream>>>(ws + OFF_SCORES);

  // 6. out = attn @ V (compact A, causal K-limit, longest-first)
  gemm_pv<<<dim3(SS / 128, HH / 128, BB), 256, 0, stream>>>(
      ws + OFF_SCORES, Vt, (float*)d_out);

  // 7. masked query rows -> uniform mean of V
  fixup_masked<<<BB * SS, 256, 0, stream>>>((float*)d_out, mask, meanV);
}

// Round 7
// 365.231 us; speedup vs baseline: 1.2318x; 1.0232x over previous
//
#include <hip/hip_runtime.h>
#include <stdint.h>

typedef __bf16 bf16x8 __attribute__((ext_vector_type(8)));
typedef float f32x4 __attribute__((ext_vector_type(4)));

#define BB 8
#define SS 2048
#define HH 1024

// compact triangular scores: 128x128 tiles. row slot 512B fp32 / first 256B
// bf16 after softmax. 16x16 grid -> 136 tiles per batch.
#define TILE_B   65536ll
#define NTRI     136
#define BATCH_B  (NTRI * TILE_B)

// ws layout (bytes). Peak ~169 MiB (validated r3-r6).
#define OFF_Q      0ll
#define OFF_K      33554432ll
#define OFF_VT     67108864ll
#define OFF_MASK   100663296ll
#define OFF_MEANV  100679680ll
#define OFF_TMP    101711872ll
#define OFF_XBF    (OFF_TMP)
#define OFF_WBF    (OFF_TMP + 33554432ll)
#define OFF_V      (OFF_TMP + 39845888ll)
#define OFF_SCORES (OFF_TMP)

__device__ __forceinline__ unsigned short f2bf(float f) {
  unsigned int u = __float_as_uint(f);
  u += 0x7FFFu + ((u >> 16) & 1u);   // RTNE
  return (unsigned short)(u >> 16);
}
__device__ __forceinline__ float bf2f(unsigned short u) {
  return __uint_as_float(((unsigned int)u) << 16);
}

__device__ __forceinline__ void gl_lds16(const void* g, void* l) {
  __builtin_amdgcn_global_load_lds(
      (const __attribute__((address_space(1))) void*)g,
      (__attribute__((address_space(3))) void*)l, 16, 0, 0);
}

// ---------------- mask canonicalizer (uint8 / int32 / float32) --------------
__global__ void canon_mask(const unsigned char* __restrict__ m,
                           unsigned char* __restrict__ out, int n) {
  __shared__ int cnt[4];
  const int t = threadIdx.x;
  if (t < 4) cnt[t] = 0;
  __syncthreads();
  int loc[4] = {0, 0, 0, 0};
  for (int i = t; i < n; i += 256)
    if (m[i] != 0) loc[i & 3]++;
  for (int r = 0; r < 4; ++r)
    if (loc[r]) atomicAdd(&cnt[r], loc[r]);
  __syncthreads();
  const int c0 = cnt[0], c1 = cnt[1], c2 = cnt[2], c3 = cnt[3];
  if (c0 > 0 && c1 == 0 && c2 == 0 && c3 == 0) {        // int32 0/1
    const int* mi = (const int*)m;
    for (int i = t; i < n; i += 256) out[i] = mi[i] ? 1 : 0;
  } else if (c0 == 0 && (c2 > 0 || c3 > 0)) {           // float32
    const float* mf = (const float*)m;
    for (int i = t; i < n; i += 256) out[i] = (mf[i] != 0.0f) ? 1 : 0;
  } else {                                              // uint8 bool
    for (int i = t; i < n; i += 256) out[i] = m[i] ? 1 : 0;
  }
}

__global__ void cvt_f32_bf16(const float* __restrict__ in,
                             unsigned short* __restrict__ out, int n4) {
  int i = blockIdx.x * blockDim.x + threadIdx.x;
  int stride = gridDim.x * blockDim.x;
  for (; i < n4; i += stride) {
    float4 v = ((const float4*)in)[i];
    ushort4 o;
    o.x = f2bf(v.x); o.y = f2bf(v.y); o.z = f2bf(v.z); o.w = f2bf(v.w);
    ((ushort4*)out)[i] = o;
  }
}

__global__ void cvt_w3(const float* __restrict__ Wq, const float* __restrict__ Wk,
                       const float* __restrict__ Wv, unsigned short* __restrict__ out) {
  const int z = blockIdx.y;
  const float* src = (z == 0) ? Wq : (z == 1) ? Wk : Wv;
  unsigned short* dst = out + (long)z * (HH * HH);
  const int n4 = HH * HH / 4;
  int i = blockIdx.x * 256 + threadIdx.x;
  for (; i < n4; i += 256 * 256) {
    float4 v = ((const float4*)src)[i];
    ushort4 o;
    o.x = f2bf(v.x); o.y = f2bf(v.y); o.z = f2bf(v.z); o.w = f2bf(v.w);
    ((ushort4*)dst)[i] = o;
  }
}

// V [S,H] -> Vt [H,S] per batch, 64x64 tiles, vectorized
__global__ __launch_bounds__(256) void transpose_v(
    const unsigned short* __restrict__ V, unsigned short* __restrict__ Vt) {
  __shared__ unsigned short t[64][66];
  const int b = blockIdx.z;
  const unsigned short* Vb = V + (size_t)b * SS * HH;
  unsigned short* Vtb = Vt + (size_t)b * SS * HH;
  const int x0 = blockIdx.x * 64;
  const int y0 = blockIdx.y * 64;
  const int tid = threadIdx.x;
  const int lr = tid >> 4;
  const int lc = (tid & 15) * 4;
#pragma unroll
  for (int i = 0; i < 4; ++i) {
    const int row = i * 16 + lr;
    *(ushort4*)&t[row][lc] =
        *(const ushort4*)(Vb + (size_t)(y0 + row) * HH + x0 + lc);
  }
  __syncthreads();
#pragma unroll
  for (int i = 0; i < 4; ++i) {
    const int c = i * 16 + lr;
    ushort4 o;
    o.x = t[lc + 0][c]; o.y = t[lc + 1][c];
    o.z = t[lc + 2][c]; o.w = t[lc + 3][c];
    *(ushort4*)(Vtb + (size_t)(x0 + c) * SS + y0 + lc) = o;
  }
}

__global__ __launch_bounds__(256) void meanv_sum(
    const unsigned short* __restrict__ Vt, float* __restrict__ out) {
  const int b = blockIdx.y;
  const int wave = threadIdx.x >> 6, lane = threadIdx.x & 63;
  const int h = blockIdx.x * 4 + wave;
  const unsigned short* row = Vt + ((long)b * HH + h) * SS;
  float s = 0.f;
#pragma unroll
  for (int j = 0; j < 4; ++j) {
    const ushort4* p = (const ushort4*)(row + j * 512 + lane * 8);
    ushort4 u0 = p[0], u1 = p[1];
    s += bf2f(u0.x) + bf2f(u0.y) + bf2f(u0.z) + bf2f(u0.w)
       + bf2f(u1.x) + bf2f(u1.y) + bf2f(u1.z) + bf2f(u1.w);
  }
#pragma unroll
  for (int off = 32; off > 0; off >>= 1) s += __shfl_down(s, off, 64);
  if (lane == 0) out[(long)b * HH + h] = s;
}

__global__ __launch_bounds__(256) void fixup_masked(
    float* __restrict__ out, const unsigned char* __restrict__ mask,
    const float* __restrict__ sums) {
  const long row = blockIdx.x;
  if (mask[row]) return;
  const long b = row >> 11;
  const int t = threadIdx.x;
  float4 v = ((const float4*)(sums + b * HH))[t];
  v.x *= (1.f / 2048.f); v.y *= (1.f / 2048.f);
  v.z *= (1.f / 2048.f); v.w *= (1.f / 2048.f);
  ((float4*)(out + row * HH))[t] = v;
}

// ============ 256x256 fused QKV — m201-style 8-phase schedule ===============
// BK=64. LDS = 2 K-tile buffers x 64KB: {A-H0@0, A-H1@16K, B-H0@32K, B-H1@48K},
// half = 128 rows x 128B, swizzle slot^=(row&7) (16B slots).
// 8 waves = 2M x 4N; wave tile 128x64; acc[8][4].
// Iter i: phases 0-3 = K-tile 2i (buf0) quadrants (mh0nh0, mh0nh1, mh1nh1,
// mh1nh0); phases 4-7 = K-tile 2i+1 (buf1). One half-tile staged per phase
// (type = g&3 -> B0,B1,A0,A1 rotation verified WAR-safe against the quadrant
// consumption order). vmcnt(4) at g3/g7 only (vmcnt(0) at final g3).
__global__ __launch_bounds__(512, 2) void gemm256(
    const unsigned short* __restrict__ Abase,
    const unsigned short* __restrict__ Bbase, long bStride,
    char* __restrict__ Cq, char* __restrict__ Ck, char* __restrict__ Cv,
    const float* __restrict__ biasq, const float* __restrict__ biask,
    const float* __restrict__ biasv) {
  extern __shared__ char smem[];
  const int tid = threadIdx.x;
  const int wave = tid >> 6, lane = tid & 63;
  const int wr = wave >> 2, wc = wave & 3;
  const int l15 = lane & 15, l4 = lane >> 4;
  const int bz = blockIdx.z;
  const int bm = blockIdx.x, bn = blockIdx.y;

  const char* A = (const char*)Abase;
  const char* B = (const char*)(Bbase + (long)bz * bStride);

  // staging source: thread s covers LDS (row = c*64 + s>>3, slot' = s&7);
  // global slot = slot' ^ (row&7) = (s&7) ^ ((s>>3)&7)  [inverse swizzle]
  const int srow = tid >> 3;
  const int gslot = (tid & 7) ^ (srow & 7);
  const char* gA = A + ((long)bm * 256 + srow) * 2048 + gslot * 16;
  const char* gB = B + ((long)bn * 256 + srow) * 2048 + gslot * 16;
  const int ldsStageW = wave << 10;     // HW adds lane*16

  // STG(kt, type, bufS): type 0=A-H0 1=A-H1 2=B-H0 3=B-H1 (compile-time)
#define STG(kt_, type_, buf_) do { \
    const char* _g = (((type_) < 2) ? gA : gB) + \
                     (((type_) & 1) ? 262144 : 0) + ((long)(kt_) << 7); \
    char* _l = smem + ((buf_) << 16) + (((type_) >> 1) << 15) + \
               (((type_) & 1) << 14) + ldsStageW; \
    gl_lds16(_g, _l); \
    gl_lds16(_g + 131072, _l + 8192); } while (0)

  // ds-read offsets (swizzled): row within half, &7 == l15&7 always
  const int sw0 = ((l4 ^ (l15 & 7)) << 4);
  const int sw1 = (((4 + l4) ^ (l15 & 7)) << 4);
  const int aB0 = (wr << 14) + l15 * 128 + sw0;
  const int aB1 = (wr << 14) + l15 * 128 + sw1;
  const int bB0 = 32768 + ((wc >> 1) << 14) + (((wc & 1) << 6) + l15) * 128 + sw0;
  const int bB1 = 32768 + ((wc >> 1) << 14) + (((wc & 1) << 6) + l15) * 128 + sw1;

  f32x4 acc[8][4];
  const f32x4 z4 = {0.f, 0.f, 0.f, 0.f};
#pragma unroll
  for (int m = 0; m < 8; ++m)
#pragma unroll
    for (int n = 0; n < 4; ++n) acc[m][n] = z4;

  // prologue: stage kt0 -> buf0, kt1 -> buf1 (16 loads); wait kt0
  STG(0, 0, 0); STG(0, 1, 0); STG(0, 2, 0); STG(0, 3, 0);
  STG(1, 0, 1); STG(1, 1, 1); STG(1, 2, 1); STG(1, 3, 1);
  asm volatile("s_waitcnt vmcnt(8)" ::: "memory");
  __builtin_amdgcn_s_barrier();
  __builtin_amdgcn_sched_barrier(0);

  bf16x8 aC[4][2], bLo[2][2], bHi[2][2];

  for (int it = 0; it < 8; ++it) {
#pragma unroll
    for (int g = 0; g < 8; ++g) {
      const int buf = (g < 4) ? 0 : 65536;
      const int q = g & 3;
      // ---- ds reads for this quadrant ----
      if (q == 0) {                       // A-lo (mh0) + B-lo (nh0)
#pragma unroll
        for (int mm = 0; mm < 4; ++mm) {
          aC[mm][0] = *(const bf16x8*)(smem + buf + aB0 + mm * 2048);
          aC[mm][1] = *(const bf16x8*)(smem + buf + aB1 + mm * 2048);
        }
#pragma unroll
        for (int nn = 0; nn < 2; ++nn) {
          bLo[nn][0] = *(const bf16x8*)(smem + buf + bB0 + nn * 2048);
          bLo[nn][1] = *(const bf16x8*)(smem + buf + bB1 + nn * 2048);
        }
      } else if (q == 1) {                // B-hi (nh1)
#pragma unroll
        for (int nn = 0; nn < 2; ++nn) {
          bHi[nn][0] = *(const bf16x8*)(smem + buf + bB0 + (2 + nn) * 2048);
          bHi[nn][1] = *(const bf16x8*)(smem + buf + bB1 + (2 + nn) * 2048);
        }
      } else if (q == 2) {                // A-hi (mh1)
#pragma unroll
        for (int mm = 0; mm < 4; ++mm) {
          aC[mm][0] = *(const bf16x8*)(smem + buf + aB0 + (4 + mm) * 2048);
          aC[mm][1] = *(const bf16x8*)(smem + buf + aB1 + (4 + mm) * 2048);
        }
      }
      // ---- stage one half-tile (rotation: type = g&3 -> B0,B1,A0,A1) ----
      {
        const int u = it * 8 + g - 2;
        if (u >= 0) {
          const int kt = 2 + (u >> 2);
          if (kt < 16) {
            // stage type by phase: g0->A0 g1->A1 g2->B0 g3->B1 g4->A0(sic)...
            // derived: type = [0,1,2,3,0,1,2,3][g] remapped: B first then A
            if (g == 0)      STG(kt, 0, 1);
            else if (g == 1) STG(kt, 1, 1);
            else if (g == 2) STG(kt, 2, 0);
            else if (g == 3) STG(kt, 3, 0);
            else if (g == 4) STG(kt, 0, 0);
            else if (g == 5) STG(kt, 1, 0);
            else if (g == 6) STG(kt, 2, 1);
            else             STG(kt, 3, 1);
          }
        }
      }
      __builtin_amdgcn_s_barrier();
      asm volatile("s_waitcnt lgkmcnt(0)" ::: "memory");
      __builtin_amdgcn_sched_barrier(0);
      __builtin_amdgcn_s_setprio(1);
      // ---- 16 MFMA (one quadrant x K=64) ----
      if (q == 0) {                       // mh0 x nh0
#pragma unroll
        for (int mm = 0; mm < 4; ++mm)
#pragma unroll
          for (int nn = 0; nn < 2; ++nn) {
            acc[mm][nn] = __builtin_amdgcn_mfma_f32_16x16x32_bf16(
                aC[mm][0], bLo[nn][0], acc[mm][nn], 0, 0, 0);
            acc[mm][nn] = __builtin_amdgcn_mfma_f32_16x16x32_bf16(
                aC[mm][1], bLo[nn][1], acc[mm][nn], 0, 0, 0);
          }
      } else if (q == 1) {                // mh0 x nh1
#pragma unroll
        for (int mm = 0; mm < 4; ++mm)
#pragma unroll
          for (int nn = 0; nn < 2; ++nn) {
            acc[mm][2 + nn] = __builtin_amdgcn_mfma_f32_16x16x32_bf16(
                aC[mm][0], bHi[nn][0], acc[mm][2 + nn], 0, 0, 0);
            acc[mm][2 + nn] = __builtin_amdgcn_mfma_f32_16x16x32_bf16(
                aC[mm][1], bHi[nn][1], acc[mm][2 + nn], 0, 0, 0);
          }
      } else if (q == 2) {                // mh1 x nh1
#pragma unroll
        for (int mm = 0; mm < 4; ++mm)
#pragma unroll
          for (int nn = 0; nn < 2; ++nn) {
            acc[4 + mm][2 + nn] = __builtin_amdgcn_mfma_f32_16x16x32_bf16(
                aC[mm][0], bHi[nn][0], acc[4 + mm][2 + nn], 0, 0, 0);
            acc[4 + mm][2 + nn] = __builtin_amdgcn_mfma_f32_16x16x32_bf16(
                aC[mm][1], bHi[nn][1], acc[4 + mm][2 + nn], 0, 0, 0);
          }
      } else {                            // mh1 x nh0
#pragma unroll
        for (int mm = 0; mm < 4; ++mm)
#pragma unroll
          for (int nn = 0; nn < 2; ++nn) {
            acc[4 + mm][nn] = __builtin_amdgcn_mfma_f32_16x16x32_bf16(
                aC[mm][0], bLo[nn][0], acc[4 + mm][nn], 0, 0, 0);
            acc[4 + mm][nn] = __builtin_amdgcn_mfma_f32_16x16x32_bf16(
                aC[mm][1], bLo[nn][1], acc[4 + mm][nn], 0, 0, 0);
          }
      }
      __builtin_amdgcn_s_setprio(0);
      __builtin_amdgcn_sched_barrier(0);
      if (q == 3) {
        if (g == 3 && it == 7)
          asm volatile("s_waitcnt vmcnt(0)" ::: "memory");
        else
          asm volatile("s_waitcnt vmcnt(4)" ::: "memory");
      }
      __builtin_amdgcn_s_barrier();
      asm volatile("" ::: "memory");
    }
  }
#undef STG

  // ---- epilogue: bf16 C via XOR-swizzled LDS bounce (r6-verified) ----
  const int rl0 = (wr << 7) + (l4 << 2);
  const int cl0 = (wc << 6) + l15;
  const float* bias = (bz == 0) ? biasq : (bz == 1) ? biask : biasv;
  unsigned short* C = (unsigned short*)((bz == 0) ? Cq : (bz == 1) ? Ck : Cv);
#pragma unroll
  for (int n = 0; n < 4; ++n) {
    const int cl = cl0 + n * 16;
    const float bv = bias[bn * 256 + cl];
    const int colx = cl ^ (l4 << 4);
#pragma unroll
    for (int m = 0; m < 8; ++m) {
      const int rl = rl0 + m * 16;
#pragma unroll
      for (int r = 0; r < 4; ++r)
        *(unsigned short*)(smem + (rl + r) * 512 + colx * 2) =
            f2bf(acc[m][n][r] + bv);
    }
  }
  __syncthreads();
  const long rowg0 = (long)bm * 256;
  const long colb0 = (long)bn * 512;
#pragma unroll
  for (int i = 0; i < 16; ++i) {
    const int s2 = i * 512 + tid;
    const int row = s2 >> 5;
    const int cb = s2 & 31;
    const int lb = (row * 512 + (cb << 4)) ^ (((row >> 2) & 3) << 5);
    *(uint4*)((char*)C + (rowg0 + row) * 2048 + colb0 + (cb << 4)) =
        *(const uint4*)(smem + lb);
  }
}

// -------- 128x128 ring-4 swizzled core: SCORES (triangular, 2 blocks/CU) ----
__global__ __launch_bounds__(256, 2) void gemm128s(
    const unsigned short* __restrict__ Qb, const unsigned short* __restrict__ Kb,
    char* __restrict__ scoresBase, const unsigned char* __restrict__ maskg) {
  __shared__ __align__(16) char smem[65536];
  const int tid = threadIdx.x;
  const int wave = tid >> 6, lane = tid & 63;
  const int wr = wave >> 1, wc = wave & 1;
  const int l15 = lane & 15, l4 = lane >> 4;
  const int bz = blockIdx.y;

  int t0 = blockIdx.x, bm = 0, a_ = 0;
  while (a_ + bm + 1 <= t0) { ++bm; a_ += bm; }
  const int bn = t0 - a_;

  const unsigned short* A = Qb + (long)bz * SS * HH;
  const unsigned short* B = Kb + (long)bz * SS * HH;

  const int s0 = tid, s1 = tid + 256;
  const int rA0 = ((s0 >> 3) << 1) | (((s0 >> 2) & 1) ^ ((s0 >> 4) & 1));
  const int cA0 = (s0 & 3) ^ (rA0 & 3);
  const int rA1 = ((s1 >> 3) << 1) | (((s1 >> 2) & 1) ^ ((s1 >> 4) & 1));
  const int cA1 = (s1 & 3) ^ (rA1 & 3);
  const char* aG0 = (const char*)A + (long)(bm * 128 + rA0) * 2048 + cA0 * 16;
  const char* aG1 = (const char*)A + (long)(bm * 128 + rA1) * 2048 + cA1 * 16;
  const char* bG0 = (const char*)B + (long)(bn * 128 + rA0) * 2048 + cA0 * 16;
  const char* bG1 = (const char*)B + (long)(bn * 128 + rA1) * 2048 + cA1 * 16;
  const int ldsL0 = wave << 10;
  const int ldsL1 = 4096 + (wave << 10);

#define STG(t_) do { \
    char* _p = smem + (((t_) & 3) << 14); \
    const long _ko = (long)(t_) << 6; \
    gl_lds16(aG0 + _ko, _p + ldsL0); \
    gl_lds16(aG1 + _ko, _p + ldsL1); \
    gl_lds16(bG0 + _ko, _p + 8192 + ldsL0); \
    gl_lds16(bG1 + _ko, _p + 8192 + ldsL1); } while (0)

  const int baseSwz = ((l15 * 64 + (l4 << 4)) ^ ((l15 & 7) << 4));
  const int rdA = (wr << 12) + baseSwz;
  const int rdB = 8192 + (wc << 12) + baseSwz;

  f32x4 acc[4][4];
  const f32x4 z4 = {0.f, 0.f, 0.f, 0.f};
#pragma unroll
  for (int m = 0; m < 4; ++m)
#pragma unroll
    for (int n = 0; n < 4; ++n) acc[m][n] = z4;

  STG(0); STG(1); STG(2);
  asm volatile("s_waitcnt vmcnt(8)" ::: "memory");
  __builtin_amdgcn_s_barrier();
  __builtin_amdgcn_sched_barrier(0);

  const int kT = 32;
  for (int t = 0; t < kT; ++t) {
    if (t + 3 < kT) STG(t + 3);
    const char* bufp = smem + ((t & 3) << 14);
    bf16x8 af[4], bg[4];
#pragma unroll
    for (int m = 0; m < 4; ++m)
      af[m] = *(const bf16x8*)(bufp + rdA + (m << 10));
#pragma unroll
    for (int n = 0; n < 4; ++n)
      bg[n] = *(const bf16x8*)(bufp + rdB + (n << 10));
    __builtin_amdgcn_s_setprio(1);
#pragma unroll
    for (int m = 0; m < 4; ++m)
#pragma unroll
      for (int n = 0; n < 4; ++n)
        acc[m][n] = __builtin_amdgcn_mfma_f32_16x16x32_bf16(af[m], bg[n],
                                                            acc[m][n], 0, 0, 0);
    __builtin_amdgcn_s_setprio(0);
    __builtin_amdgcn_sched_barrier(0);
    if (t + 3 < kT)       asm volatile("s_waitcnt vmcnt(8)" ::: "memory");
    else if (t + 3 == kT) asm volatile("s_waitcnt vmcnt(4)" ::: "memory");
    else if (t + 2 == kT) asm volatile("s_waitcnt vmcnt(0)" ::: "memory");
    if (t + 1 < kT) {
      __builtin_amdgcn_s_barrier();
      __builtin_amdgcn_sched_barrier(0);
      asm volatile("" ::: "memory");
    }
  }
#undef STG

  const int rl0 = (wr << 6) + (l4 << 2);
  const int cl0 = (wc << 6) + l15;
  char* Ct = scoresBase + (long)bz * BATCH_B + (long)t0 * TILE_B;
  const unsigned char* mrow = maskg + (long)bz * SS;
  bool km[4]; int kg[4];
#pragma unroll
  for (int n = 0; n < 4; ++n) {
    kg[n] = bn * 128 + cl0 + n * 16;
    km[n] = mrow[kg[n]] != 0;
  }
  __syncthreads();
#pragma unroll
  for (int m = 0; m < 4; ++m)
#pragma unroll
    for (int r = 0; r < 4; ++r) {
      const int ql = rl0 + m * 16 + r;
      const int q = bm * 128 + ql;
      const bool qm = mrow[q] != 0;
#pragma unroll
      for (int n = 0; n < 4; ++n) {
        float v;
        if (!qm) v = 0.0f;
        else if (kg[n] <= q && km[n]) v = acc[m][n][r] * 0.03125f;
        else v = -1.0e9f;
        const int colx = (cl0 + n * 16) ^ (l4 << 4);
        *(float*)(smem + ql * 512 + colx * 4) = v;
      }
    }
  __syncthreads();
#pragma unroll
  for (int i = 0; i < 16; ++i) {
    const int s2 = i * 256 + tid;
    const int row = s2 >> 5;
    const int cb = s2 & 31;
    const int lb = (row * 512 + (cb << 4)) ^ (((row >> 2) & 3) << 6);
    *(uint4*)(Ct + (long)row * 512 + (cb << 4)) = *(const uint4*)(smem + lb);
  }
}

// ---------------- softmax over causal prefix, compact 128-tiles -------------
__global__ __launch_bounds__(256) void softmax_tri(char* __restrict__ base) {
  const int r = blockIdx.x;
  const int bz = blockIdx.y;
  const int bm = r >> 7;
  const int w = (bm + 1) << 7;
  char* bb = base + (long)bz * BATCH_B +
             (long)(bm * (bm + 1) / 2) * TILE_B + (long)(r & 127) * 512;
  const int t = threadIdx.x;
  const bool act = (t << 3) < w;
  const int bn = t >> 4;
  const int cl = (t << 3) & 127;
  const char* src = bb + (long)bn * TILE_B + (long)cl * 4;
  float v[8];
  float m = -3.0e38f;
  if (act) {
    float4 a = ((const float4*)src)[0];
    float4 b2 = ((const float4*)src)[1];
    v[0] = a.x; v[1] = a.y; v[2] = a.z; v[3] = a.w;
    v[4] = b2.x; v[5] = b2.y; v[6] = b2.z; v[7] = b2.w;
#pragma unroll
    for (int k = 0; k < 8; ++k) m = fmaxf(m, v[k]);
  }
  __shared__ float red[8];
#pragma unroll
  for (int off = 32; off > 0; off >>= 1) m = fmaxf(m, __shfl_down(m, off, 64));
  const int wid = t >> 6, lane = t & 63;
  if (lane == 0) red[wid] = m;
  __syncthreads();
  m = fmaxf(fmaxf(red[0], red[1]), fmaxf(red[2], red[3]));
  float e[8];
  float s = 0.f;
  if (act) {
#pragma unroll
    for (int k = 0; k < 8; ++k) { e[k] = __expf(v[k] - m); s += e[k]; }
  }
#pragma unroll
  for (int off = 32; off > 0; off >>= 1) s += __shfl_down(s, off, 64);
  if (lane == 0) red[4 + wid] = s;
  __syncthreads();
  s = red[4] + red[5] + red[6] + red[7];
  const float inv = 1.0f / s;
  if (act) {
    ushort4 o0, o1;
    o0.x = f2bf(e[0] * inv); o0.y = f2bf(e[1] * inv);
    o0.z = f2bf(e[2] * inv); o0.w = f2bf(e[3] * inv);
    o1.x = f2bf(e[4] * inv); o1.y = f2bf(e[5] * inv);
    o1.z = f2bf(e[6] * inv); o1.w = f2bf(e[7] * inv);
    ushort4* dst = (ushort4*)(bb + (long)bn * TILE_B + (long)cl * 2);
    dst[0] = o0;
    dst[1] = o1;
  }
}

// -------- 128x128 ring-4 swizzled core: PV (causal K-limit, 2 blocks/CU) ----
__global__ __launch_bounds__(256, 2) void gemm_pv(
    const char* __restrict__ attn, const unsigned short* __restrict__ VtB,
    float* __restrict__ Out) {
  __shared__ __align__(16) char smem[65536];
  const int tid = threadIdx.x;
  const int wave = tid >> 6, lane = tid & 63;
  const int wr = wave >> 1, wc = wave & 1;
  const int l15 = lane & 15, l4 = lane >> 4;
  const int bz = blockIdx.z;
  const int bm = 15 - blockIdx.x;
  const int bn = blockIdx.y;

  const char* Ab = attn + (long)bz * BATCH_B + (long)(bm * (bm + 1) / 2) * TILE_B;
  const unsigned short* B = VtB + (long)bz * SS * HH;

  const int s0 = tid, s1 = tid + 256;
  const int rA0 = ((s0 >> 3) << 1) | (((s0 >> 2) & 1) ^ ((s0 >> 4) & 1));
  const int cA0 = (s0 & 3) ^ (rA0 & 3);
  const int rA1 = ((s1 >> 3) << 1) | (((s1 >> 2) & 1) ^ ((s1 >> 4) & 1));
  const int cA1 = (s1 & 3) ^ (rA1 & 3);
  const char* aB0 = Ab + (long)rA0 * 512 + cA0 * 16;
  const char* aB1 = Ab + (long)rA1 * 512 + cA1 * 16;
  const char* bG0 = (const char*)(B + (long)(bn * 128 + rA0) * SS) + cA0 * 16;
  const char* bG1 = (const char*)(B + (long)(bn * 128 + rA1) * SS) + cA1 * 16;
  const int ldsL0 = wave << 10;
  const int ldsL1 = 4096 + (wave << 10);

#define STGPV(t_) do { \
    char* _p = smem + (((t_) & 3) << 14); \
    const long _aO = (long)((t_) >> 2) * TILE_B + (long)((t_) & 3) * 64; \
    const long _bO = (long)(t_) << 6; \
    gl_lds16(aB0 + _aO, _p + ldsL0); \
    gl_lds16(aB1 + _aO, _p + ldsL1); \
    gl_lds16(bG0 + _bO, _p + 8192 + ldsL0); \
    gl_lds16(bG1 + _bO, _p + 8192 + ldsL1); } while (0)

  const int baseSwz = ((l15 * 64 + (l4 << 4)) ^ ((l15 & 7) << 4));
  const int rdA = (wr << 12) + baseSwz;
  const int rdB = 8192 + (wc << 12) + baseSwz;

  f32x4 acc[4][4];
  const f32x4 z4 = {0.f, 0.f, 0.f, 0.f};
#pragma unroll
  for (int m = 0; m < 4; ++m)
#pragma unroll
    for (int n = 0; n < 4; ++n) acc[m][n] = z4;

  STGPV(0); STGPV(1); STGPV(2);
  asm volatile("s_waitcnt vmcnt(8)" ::: "memory");
  __builtin_amdgcn_s_barrier();
  __builtin_amdgcn_sched_barrier(0);

  const int kT = (bm + 1) * 4;
  for (int t = 0; t < kT; ++t) {
    if (t + 3 < kT) STGPV(t + 3);
    const char* bufp = smem + ((t & 3) << 14);
    bf16x8 af[4], bg[4];
#pragma unroll
    for (int m = 0; m < 4; ++m)
      af[m] = *(const bf16x8*)(bufp + rdA + (m << 10));
#pragma unroll
    for (int n = 0; n < 4; ++n)
      bg[n] = *(const bf16x8*)(bufp + rdB + (n << 10));
    __builtin_amdgcn_s_setprio(1);
#pragma unroll
    for (int m = 0; m < 4; ++m)
#pragma unroll
      for (int n = 0; n < 4; ++n)
        acc[m][n] = __builtin_amdgcn_mfma_f32_16x16x32_bf16(af[m], bg[n],
                                                            acc[m][n], 0, 0, 0);
    __builtin_amdgcn_s_setprio(0);
    __builtin_amdgcn_sched_barrier(0);
    if (t + 3 < kT)       asm volatile("s_waitcnt vmcnt(8)" ::: "memory");
    else if (t + 3 == kT) asm volatile("s_waitcnt vmcnt(4)" ::: "memory");
    else if (t + 2 == kT) asm volatile("s_waitcnt vmcnt(0)" ::: "memory");
    if (t + 1 < kT) {
      __builtin_amdgcn_s_barrier();
      __builtin_amdgcn_sched_barrier(0);
      asm volatile("" ::: "memory");
    }
  }
#undef STGPV

  const int rl0 = (wr << 6) + (l4 << 2);
  const int cl0 = (wc << 6) + l15;
  __syncthreads();
#pragma unroll
  for (int m = 0; m < 4; ++m)
#pragma unroll
    for (int r = 0; r < 4; ++r) {
      const int ql = rl0 + m * 16 + r;
#pragma unroll
      for (int n = 0; n < 4; ++n) {
        const int colx = (cl0 + n * 16) ^ (l4 << 4);
        *(float*)(smem + ql * 512 + colx * 4) = acc[m][n][r];
      }
    }
  __syncthreads();
  char* Ob = (char*)(Out + ((long)bz * SS + bm * 128) * HH + bn * 128);
#pragma unroll
  for (int i = 0; i < 16; ++i) {
    const int s2 = i * 256 + tid;
    const int row = s2 >> 5;
    const int cb = s2 & 31;
    const int lb = (row * 512 + (cb << 4)) ^ (((row >> 2) & 3) << 6);
    *(uint4*)(Ob + (long)row * 4096 + (cb << 4)) = *(const uint4*)(smem + lb);
  }
}

extern "C" void kernel_launch(void* const* d_in, const int* in_sizes, int n_in,
                              void* d_out, int out_size, void* d_ws, size_t ws_size,
                              hipStream_t stream) {
  (void)in_sizes; (void)n_in; (void)out_size; (void)ws_size;
  const float* x = (const float*)d_in[0];
  const unsigned char* mask_raw = (const unsigned char*)d_in[1];
  const float* Wq = (const float*)d_in[2];
  const float* bq = (const float*)d_in[3];
  const float* Wk = (const float*)d_in[4];
  const float* bk = (const float*)d_in[5];
  const float* Wv = (const float*)d_in[6];
  const float* bv = (const float*)d_in[7];
  char* ws = (char*)d_ws;

  unsigned short* Xbf = (unsigned short*)(ws + OFF_XBF);
  unsigned short* Wbf = (unsigned short*)(ws + OFF_WBF);
  unsigned short* Qb = (unsigned short*)(ws + OFF_Q);
  unsigned short* Kb = (unsigned short*)(ws + OFF_K);
  unsigned short* Vb = (unsigned short*)(ws + OFF_V);
  unsigned short* Vt = (unsigned short*)(ws + OFF_VT);
  unsigned char* mask = (unsigned char*)(ws + OFF_MASK);
  float* meanV = (float*)(ws + OFF_MEANV);

  const long MS = (long)BB * SS;  // 16384

  (void)hipFuncSetAttribute((const void*)gemm256,
                            hipFuncAttributeMaxDynamicSharedMemorySize, 131072);

  // 0. canonicalize mask
  canon_mask<<<1, 256, 0, stream>>>(mask_raw, mask, (int)(BB * SS));

  // 1. fp32 -> bf16
  cvt_f32_bf16<<<2048, 256, 0, stream>>>(x, Xbf, (int)(MS * HH / 4));
  cvt_w3<<<dim3(256, 3), 256, 0, stream>>>(Wq, Wk, Wv, Wbf);

  // 2. fused QKV projection (8-phase 256^2 core): grid (64,4,3)
  gemm256<<<dim3(MS / 256, HH / 256, 3), 512, 131072, stream>>>(
      Xbf, Wbf, (long)HH * HH,
      (char*)Qb, (char*)Kb, (char*)Vb, bq, bk, bv);

  // 3. V -> Vt ; column sums for masked-row fixup
  transpose_v<<<dim3(HH / 64, SS / 64, BB), 256, 0, stream>>>(Vb, Vt);
  meanv_sum<<<dim3(HH / 4, BB), 256, 0, stream>>>(Vt, meanV);

  // 4. scores: 128^2 triangular tiles: grid (136,8)
  gemm128s<<<dim3(NTRI, BB), 256, 0, stream>>>(
      Qb, Kb, ws + OFF_SCORES, mask);

  // 5. softmax over causal prefix, in-place -> compact bf16
  softmax_tri<<<dim3(SS, BB), 256, 0, stream>>>(ws + OFF_SCORES);

  // 6. out = attn @ V (compact A, causal K-limit, longest-first)
  gemm_pv<<<dim3(SS / 128, HH / 128, BB), 256, 0, stream>>>(
      ws + OFF_SCORES, Vt, (float*)d_out);

  // 7. masked query rows -> uniform mean of V
  fixup_masked<<<BB * SS, 256, 0, stream>>>((float*)d_out, mask, meanV);
}

// Round 8
// 359.721 us; speedup vs baseline: 1.2506x; 1.0153x over previous
//
#include <hip/hip_runtime.h>
#include <stdint.h>

typedef __bf16 bf16x8 __attribute__((ext_vector_type(8)));
typedef float f32x4 __attribute__((ext_vector_type(4)));

#define BB 8
#define SS 2048
#define HH 1024

// compact triangular scores: 128x128 tiles, bf16 THROUGHOUT.
// row slot = 256B. 16x16 grid -> 136 lower tiles per batch.
#define TILE_B   32768ll
#define NTRI     136
#define BATCH_B  (NTRI * TILE_B)   // 4,456,448 B per batch (35.6 MB total)

// ws layout (bytes). Peak ~140 MiB.
// Q [0,32M) | K [32M,64M) | Vt [64M,96M) | mask 16K | meanV 4K | TMP [97M..)
// TMP phase A: Xbf(32M)+Wbf(6M); TMP phase B: bf16 scores 35.6M (overlays)
#define OFF_Q      0ll
#define OFF_K      33554432ll
#define OFF_VT     67108864ll
#define OFF_MASK   100663296ll
#define OFF_MEANV  100679680ll
#define OFF_TMP    101711872ll
#define OFF_XBF    (OFF_TMP)
#define OFF_WBF    (OFF_TMP + 33554432ll)
#define OFF_SCORES (OFF_TMP)

__device__ __forceinline__ unsigned short f2bf(float f) {
  unsigned int u = __float_as_uint(f);
  u += 0x7FFFu + ((u >> 16) & 1u);   // RTNE
  return (unsigned short)(u >> 16);
}
__device__ __forceinline__ float bf2f(unsigned short u) {
  return __uint_as_float(((unsigned int)u) << 16);
}

__device__ __forceinline__ void gl_lds16(const void* g, void* l) {
  __builtin_amdgcn_global_load_lds(
      (const __attribute__((address_space(1))) void*)g,
      (__attribute__((address_space(3))) void*)l, 16, 0, 0);
}

// ---------------- mask canonicalizer (uint8 / int32 / float32) --------------
__global__ void canon_mask(const unsigned char* __restrict__ m,
                           unsigned char* __restrict__ out, int n) {
  __shared__ int cnt[4];
  const int t = threadIdx.x;
  if (t < 4) cnt[t] = 0;
  __syncthreads();
  int loc[4] = {0, 0, 0, 0};
  for (int i = t; i < n; i += 256)
    if (m[i] != 0) loc[i & 3]++;
  for (int r = 0; r < 4; ++r)
    if (loc[r]) atomicAdd(&cnt[r], loc[r]);
  __syncthreads();
  const int c0 = cnt[0], c1 = cnt[1], c2 = cnt[2], c3 = cnt[3];
  if (c0 > 0 && c1 == 0 && c2 == 0 && c3 == 0) {        // int32 0/1
    const int* mi = (const int*)m;
    for (int i = t; i < n; i += 256) out[i] = mi[i] ? 1 : 0;
  } else if (c0 == 0 && (c2 > 0 || c3 > 0)) {           // float32
    const float* mf = (const float*)m;
    for (int i = t; i < n; i += 256) out[i] = (mf[i] != 0.0f) ? 1 : 0;
  } else {                                              // uint8 bool
    for (int i = t; i < n; i += 256) out[i] = m[i] ? 1 : 0;
  }
}

__global__ void cvt_f32_bf16(const float* __restrict__ in,
                             unsigned short* __restrict__ out, int n4) {
  int i = blockIdx.x * blockDim.x + threadIdx.x;
  int stride = gridDim.x * blockDim.x;
  for (; i < n4; i += stride) {
    float4 v = ((const float4*)in)[i];
    ushort4 o;
    o.x = f2bf(v.x); o.y = f2bf(v.y); o.z = f2bf(v.z); o.w = f2bf(v.w);
    ((ushort4*)out)[i] = o;
  }
}

__global__ void cvt_w3(const float* __restrict__ Wq, const float* __restrict__ Wk,
                       const float* __restrict__ Wv, unsigned short* __restrict__ out) {
  const int z = blockIdx.y;
  const float* src = (z == 0) ? Wq : (z == 1) ? Wk : Wv;
  unsigned short* dst = out + (long)z * (HH * HH);
  const int n4 = HH * HH / 4;
  int i = blockIdx.x * 256 + threadIdx.x;
  for (; i < n4; i += 256 * 256) {
    float4 v = ((const float4*)src)[i];
    ushort4 o;
    o.x = f2bf(v.x); o.y = f2bf(v.y); o.z = f2bf(v.z); o.w = f2bf(v.w);
    ((ushort4*)dst)[i] = o;
  }
}

__global__ __launch_bounds__(256) void meanv_sum(
    const unsigned short* __restrict__ Vt, float* __restrict__ out) {
  const int b = blockIdx.y;
  const int wave = threadIdx.x >> 6, lane = threadIdx.x & 63;
  const int h = blockIdx.x * 4 + wave;
  const unsigned short* row = Vt + ((long)b * HH + h) * SS;
  float s = 0.f;
#pragma unroll
  for (int j = 0; j < 4; ++j) {
    const ushort4* p = (const ushort4*)(row + j * 512 + lane * 8);
    ushort4 u0 = p[0], u1 = p[1];
    s += bf2f(u0.x) + bf2f(u0.y) + bf2f(u0.z) + bf2f(u0.w)
       + bf2f(u1.x) + bf2f(u1.y) + bf2f(u1.z) + bf2f(u1.w);
  }
#pragma unroll
  for (int off = 32; off > 0; off >>= 1) s += __shfl_down(s, off, 64);
  if (lane == 0) out[(long)b * HH + h] = s;
}

__global__ __launch_bounds__(256) void fixup_masked(
    float* __restrict__ out, const unsigned char* __restrict__ mask,
    const float* __restrict__ sums) {
  const long row = blockIdx.x;
  if (mask[row]) return;
  const long b = row >> 11;
  const int t = threadIdx.x;
  float4 v = ((const float4*)(sums + b * HH))[t];
  v.x *= (1.f / 2048.f); v.y *= (1.f / 2048.f);
  v.z *= (1.f / 2048.f); v.w *= (1.f / 2048.f);
  ((float4*)(out + row * HH))[t] = v;
}

// ============ 256x256 fused QKV — 8-phase schedule (r7-verified core) =======
// bz==2 epilogue writes V TRANSPOSED (Vt) straight from the LDS bounce:
// kills the separate transpose kernel + the V buffer.
__global__ __launch_bounds__(512, 2) void gemm256(
    const unsigned short* __restrict__ Abase,
    const unsigned short* __restrict__ Bbase, long bStride,
    char* __restrict__ Cq, char* __restrict__ Ck, char* __restrict__ VtOut,
    const float* __restrict__ biasq, const float* __restrict__ biask,
    const float* __restrict__ biasv) {
  extern __shared__ char smem[];
  const int tid = threadIdx.x;
  const int wave = tid >> 6, lane = tid & 63;
  const int wr = wave >> 2, wc = wave & 3;
  const int l15 = lane & 15, l4 = lane >> 4;
  const int bz = blockIdx.z;
  const int bm = blockIdx.x, bn = blockIdx.y;

  const char* A = (const char*)Abase;
  const char* B = (const char*)(Bbase + (long)bz * bStride);

  const int srow = tid >> 3;
  const int gslot = (tid & 7) ^ (srow & 7);
  const char* gA = A + ((long)bm * 256 + srow) * 2048 + gslot * 16;
  const char* gB = B + ((long)bn * 256 + srow) * 2048 + gslot * 16;
  const int ldsStageW = wave << 10;

#define STG(kt_, type_, buf_) do { \
    const char* _g = (((type_) < 2) ? gA : gB) + \
                     (((type_) & 1) ? 262144 : 0) + ((long)(kt_) << 7); \
    char* _l = smem + ((buf_) << 16) + (((type_) >> 1) << 15) + \
               (((type_) & 1) << 14) + ldsStageW; \
    gl_lds16(_g, _l); \
    gl_lds16(_g + 131072, _l + 8192); } while (0)

  const int sw0 = ((l4 ^ (l15 & 7)) << 4);
  const int sw1 = (((4 + l4) ^ (l15 & 7)) << 4);
  const int aB0 = (wr << 14) + l15 * 128 + sw0;
  const int aB1 = (wr << 14) + l15 * 128 + sw1;
  const int bB0 = 32768 + ((wc >> 1) << 14) + (((wc & 1) << 6) + l15) * 128 + sw0;
  const int bB1 = 32768 + ((wc >> 1) << 14) + (((wc & 1) << 6) + l15) * 128 + sw1;

  f32x4 acc[8][4];
  const f32x4 z4 = {0.f, 0.f, 0.f, 0.f};
#pragma unroll
  for (int m = 0; m < 8; ++m)
#pragma unroll
    for (int n = 0; n < 4; ++n) acc[m][n] = z4;

  STG(0, 0, 0); STG(0, 1, 0); STG(0, 2, 0); STG(0, 3, 0);
  STG(1, 0, 1); STG(1, 1, 1); STG(1, 2, 1); STG(1, 3, 1);
  asm volatile("s_waitcnt vmcnt(8)" ::: "memory");
  __builtin_amdgcn_s_barrier();
  __builtin_amdgcn_sched_barrier(0);

  bf16x8 aC[4][2], bLo[2][2], bHi[2][2];

  for (int it = 0; it < 8; ++it) {
#pragma unroll
    for (int g = 0; g < 8; ++g) {
      const int buf = (g < 4) ? 0 : 65536;
      const int q = g & 3;
      if (q == 0) {
#pragma unroll
        for (int mm = 0; mm < 4; ++mm) {
          aC[mm][0] = *(const bf16x8*)(smem + buf + aB0 + mm * 2048);
          aC[mm][1] = *(const bf16x8*)(smem + buf + aB1 + mm * 2048);
        }
#pragma unroll
        for (int nn = 0; nn < 2; ++nn) {
          bLo[nn][0] = *(const bf16x8*)(smem + buf + bB0 + nn * 2048);
          bLo[nn][1] = *(const bf16x8*)(smem + buf + bB1 + nn * 2048);
        }
      } else if (q == 1) {
#pragma unroll
        for (int nn = 0; nn < 2; ++nn) {
          bHi[nn][0] = *(const bf16x8*)(smem + buf + bB0 + (2 + nn) * 2048);
          bHi[nn][1] = *(const bf16x8*)(smem + buf + bB1 + (2 + nn) * 2048);
        }
      } else if (q == 2) {
#pragma unroll
        for (int mm = 0; mm < 4; ++mm) {
          aC[mm][0] = *(const bf16x8*)(smem + buf + aB0 + (4 + mm) * 2048);
          aC[mm][1] = *(const bf16x8*)(smem + buf + aB1 + (4 + mm) * 2048);
        }
      }
      {
        const int u = it * 8 + g - 2;
        if (u >= 0) {
          const int kt = 2 + (u >> 2);
          if (kt < 16) {
            if (g == 0)      STG(kt, 0, 1);
            else if (g == 1) STG(kt, 1, 1);
            else if (g == 2) STG(kt, 2, 0);
            else if (g == 3) STG(kt, 3, 0);
            else if (g == 4) STG(kt, 0, 0);
            else if (g == 5) STG(kt, 1, 0);
            else if (g == 6) STG(kt, 2, 1);
            else             STG(kt, 3, 1);
          }
        }
      }
      __builtin_amdgcn_s_barrier();
      asm volatile("s_waitcnt lgkmcnt(0)" ::: "memory");
      __builtin_amdgcn_sched_barrier(0);
      __builtin_amdgcn_s_setprio(1);
      if (q == 0) {
#pragma unroll
        for (int mm = 0; mm < 4; ++mm)
#pragma unroll
          for (int nn = 0; nn < 2; ++nn) {
            acc[mm][nn] = __builtin_amdgcn_mfma_f32_16x16x32_bf16(
                aC[mm][0], bLo[nn][0], acc[mm][nn], 0, 0, 0);
            acc[mm][nn] = __builtin_amdgcn_mfma_f32_16x16x32_bf16(
                aC[mm][1], bLo[nn][1], acc[mm][nn], 0, 0, 0);
          }
      } else if (q == 1) {
#pragma unroll
        for (int mm = 0; mm < 4; ++mm)
#pragma unroll
          for (int nn = 0; nn < 2; ++nn) {
            acc[mm][2 + nn] = __builtin_amdgcn_mfma_f32_16x16x32_bf16(
                aC[mm][0], bHi[nn][0], acc[mm][2 + nn], 0, 0, 0);
            acc[mm][2 + nn] = __builtin_amdgcn_mfma_f32_16x16x32_bf16(
                aC[mm][1], bHi[nn][1], acc[mm][2 + nn], 0, 0, 0);
          }
      } else if (q == 2) {
#pragma unroll
        for (int mm = 0; mm < 4; ++mm)
#pragma unroll
          for (int nn = 0; nn < 2; ++nn) {
            acc[4 + mm][2 + nn] = __builtin_amdgcn_mfma_f32_16x16x32_bf16(
                aC[mm][0], bHi[nn][0], acc[4 + mm][2 + nn], 0, 0, 0);
            acc[4 + mm][2 + nn] = __builtin_amdgcn_mfma_f32_16x16x32_bf16(
                aC[mm][1], bHi[nn][1], acc[4 + mm][2 + nn], 0, 0, 0);
          }
      } else {
#pragma unroll
        for (int mm = 0; mm < 4; ++mm)
#pragma unroll
          for (int nn = 0; nn < 2; ++nn) {
            acc[4 + mm][nn] = __builtin_amdgcn_mfma_f32_16x16x32_bf16(
                aC[mm][0], bLo[nn][0], acc[4 + mm][nn], 0, 0, 0);
            acc[4 + mm][nn] = __builtin_amdgcn_mfma_f32_16x16x32_bf16(
                aC[mm][1], bLo[nn][1], acc[4 + mm][nn], 0, 0, 0);
          }
      }
      __builtin_amdgcn_s_setprio(0);
      __builtin_amdgcn_sched_barrier(0);
      if (q == 3) {
        if (g == 3 && it == 7)
          asm volatile("s_waitcnt vmcnt(0)" ::: "memory");
        else
          asm volatile("s_waitcnt vmcnt(4)" ::: "memory");
      }
      __builtin_amdgcn_s_barrier();
      asm volatile("" ::: "memory");
    }
  }
#undef STG

  // ---- epilogue: bf16 C via XOR-swizzled LDS bounce ----
  const int rl0 = (wr << 7) + (l4 << 2);
  const int cl0 = (wc << 6) + l15;
  const float* bias = (bz == 0) ? biasq : (bz == 1) ? biask : biasv;
#pragma unroll
  for (int n = 0; n < 4; ++n) {
    const int cl = cl0 + n * 16;
    const float bv = bias[bn * 256 + cl];
    const int colx = cl ^ (l4 << 4);
#pragma unroll
    for (int m = 0; m < 8; ++m) {
      const int rl = rl0 + m * 16;
#pragma unroll
      for (int r = 0; r < 4; ++r)
        *(unsigned short*)(smem + (rl + r) * 512 + colx * 2) =
            f2bf(acc[m][n][r] + bv);
    }
  }
  __syncthreads();
  if (bz < 2) {
    unsigned short* C = (unsigned short*)((bz == 0) ? Cq : Ck);
    const long rowg0 = (long)bm * 256;
    const long colb0 = (long)bn * 512;
#pragma unroll
    for (int i = 0; i < 16; ++i) {
      const int s2 = i * 512 + tid;
      const int row = s2 >> 5;
      const int cb = s2 & 31;
      const int lb = (row * 512 + (cb << 4)) ^ (((row >> 2) & 3) << 5);
      *(uint4*)((char*)C + (rowg0 + row) * 2048 + colb0 + (cb << 4)) =
          *(const uint4*)(smem + lb);
    }
  } else {
    // transposed store: LDS tile rows = X-rows (s), cols = h. Write Vt[h][s].
    // batch = bm>>3 (tiles never straddle: 256 | 2048).
    char* VtB = VtOut + (long)(bm >> 3) * (SS * HH * 2) + (long)(bm & 7) * 512;
#pragma unroll
    for (int i = 0; i < 16; ++i) {
      const int s2 = i * 512 + tid;
      const int h = s2 >> 5;          // 0..255
      const int cb = s2 & 31;         // s-chunk: rows cb*8..cb*8+7
      unsigned int w[4];
#pragma unroll
      for (int jj = 0; jj < 4; ++jj) {
        const int sa = cb * 8 + jj * 2;
        const int xr = ((sa >> 2) & 3) << 4;   // same for sa and sa+1
        const unsigned int lo =
            *(const unsigned short*)(smem + sa * 512 + ((h ^ xr) << 1));
        const unsigned int hi =
            *(const unsigned short*)(smem + (sa + 1) * 512 + ((h ^ xr) << 1));
        w[jj] = lo | (hi << 16);
      }
      uint4 o; o.x = w[0]; o.y = w[1]; o.z = w[2]; o.w = w[3];
      *(uint4*)(VtB + (long)(bn * 256 + h) * 4096 + cb * 16) = o;
    }
  }
}

// -------- 128x128 ring-4 swizzled core: SCORES -> compact bf16 --------------
__global__ __launch_bounds__(256, 2) void gemm128s(
    const unsigned short* __restrict__ Qb, const unsigned short* __restrict__ Kb,
    char* __restrict__ scoresBase, const unsigned char* __restrict__ maskg) {
  __shared__ __align__(16) char smem[65536];
  const int tid = threadIdx.x;
  const int wave = tid >> 6, lane = tid & 63;
  const int wr = wave >> 1, wc = wave & 1;
  const int l15 = lane & 15, l4 = lane >> 4;
  const int bz = blockIdx.y;

  int t0 = blockIdx.x, bm = 0, a_ = 0;
  while (a_ + bm + 1 <= t0) { ++bm; a_ += bm; }
  const int bn = t0 - a_;

  const unsigned short* A = Qb + (long)bz * SS * HH;
  const unsigned short* B = Kb + (long)bz * SS * HH;

  const int s0 = tid, s1 = tid + 256;
  const int rA0 = ((s0 >> 3) << 1) | (((s0 >> 2) & 1) ^ ((s0 >> 4) & 1));
  const int cA0 = (s0 & 3) ^ (rA0 & 3);
  const int rA1 = ((s1 >> 3) << 1) | (((s1 >> 2) & 1) ^ ((s1 >> 4) & 1));
  const int cA1 = (s1 & 3) ^ (rA1 & 3);
  const char* aG0 = (const char*)A + (long)(bm * 128 + rA0) * 2048 + cA0 * 16;
  const char* aG1 = (const char*)A + (long)(bm * 128 + rA1) * 2048 + cA1 * 16;
  const char* bG0 = (const char*)B + (long)(bn * 128 + rA0) * 2048 + cA0 * 16;
  const char* bG1 = (const char*)B + (long)(bn * 128 + rA1) * 2048 + cA1 * 16;
  const int ldsL0 = wave << 10;
  const int ldsL1 = 4096 + (wave << 10);

#define STG(t_) do { \
    char* _p = smem + (((t_) & 3) << 14); \
    const long _ko = (long)(t_) << 6; \
    gl_lds16(aG0 + _ko, _p + ldsL0); \
    gl_lds16(aG1 + _ko, _p + ldsL1); \
    gl_lds16(bG0 + _ko, _p + 8192 + ldsL0); \
    gl_lds16(bG1 + _ko, _p + 8192 + ldsL1); } while (0)

  const int baseSwz = ((l15 * 64 + (l4 << 4)) ^ ((l15 & 7) << 4));
  const int rdA = (wr << 12) + baseSwz;
  const int rdB = 8192 + (wc << 12) + baseSwz;

  f32x4 acc[4][4];
  const f32x4 z4 = {0.f, 0.f, 0.f, 0.f};
#pragma unroll
  for (int m = 0; m < 4; ++m)
#pragma unroll
    for (int n = 0; n < 4; ++n) acc[m][n] = z4;

  STG(0); STG(1); STG(2);
  asm volatile("s_waitcnt vmcnt(8)" ::: "memory");
  __builtin_amdgcn_s_barrier();
  __builtin_amdgcn_sched_barrier(0);

  const int kT = 32;
  for (int t = 0; t < kT; ++t) {
    if (t + 3 < kT) STG(t + 3);
    const char* bufp = smem + ((t & 3) << 14);
    bf16x8 af[4], bg[4];
#pragma unroll
    for (int m = 0; m < 4; ++m)
      af[m] = *(const bf16x8*)(bufp + rdA + (m << 10));
#pragma unroll
    for (int n = 0; n < 4; ++n)
      bg[n] = *(const bf16x8*)(bufp + rdB + (n << 10));
    __builtin_amdgcn_s_setprio(1);
#pragma unroll
    for (int m = 0; m < 4; ++m)
#pragma unroll
      for (int n = 0; n < 4; ++n)
        acc[m][n] = __builtin_amdgcn_mfma_f32_16x16x32_bf16(af[m], bg[n],
                                                            acc[m][n], 0, 0, 0);
    __builtin_amdgcn_s_setprio(0);
    __builtin_amdgcn_sched_barrier(0);
    if (t + 3 < kT)       asm volatile("s_waitcnt vmcnt(8)" ::: "memory");
    else if (t + 3 == kT) asm volatile("s_waitcnt vmcnt(4)" ::: "memory");
    else if (t + 2 == kT) asm volatile("s_waitcnt vmcnt(0)" ::: "memory");
    if (t + 1 < kT) {
      __builtin_amdgcn_s_barrier();
      __builtin_amdgcn_sched_barrier(0);
      asm volatile("" ::: "memory");
    }
  }
#undef STG

  // epilogue: masked bf16 compact write via XOR-swizzled LDS bounce (32 KB)
  const int rl0 = (wr << 6) + (l4 << 2);
  const int cl0 = (wc << 6) + l15;
  char* Ct = scoresBase + (long)bz * BATCH_B + (long)t0 * TILE_B;
  const unsigned char* mrow = maskg + (long)bz * SS;
  bool km[4]; int kg[4];
#pragma unroll
  for (int n = 0; n < 4; ++n) {
    kg[n] = bn * 128 + cl0 + n * 16;
    km[n] = mrow[kg[n]] != 0;
  }
  __syncthreads();
#pragma unroll
  for (int m = 0; m < 4; ++m)
#pragma unroll
    for (int r = 0; r < 4; ++r) {
      const int ql = rl0 + m * 16 + r;
      const int q = bm * 128 + ql;
      const bool qm = mrow[q] != 0;
#pragma unroll
      for (int n = 0; n < 4; ++n) {
        float v;
        if (!qm) v = 0.0f;
        else if (kg[n] <= q && km[n]) v = acc[m][n][r] * 0.03125f;
        else v = -1.0e9f;
        const int colx = (cl0 + n * 16) ^ (l4 << 4);
        *(unsigned short*)(smem + ql * 256 + colx * 2) = f2bf(v);
      }
    }
  __syncthreads();
#pragma unroll
  for (int i = 0; i < 8; ++i) {
    const int s2 = i * 256 + tid;
    const int row = s2 >> 4;
    const int cb = s2 & 15;
    const int lb = row * 256 + ((cb << 4) ^ (((row >> 2) & 3) << 5));
    *(uint4*)(Ct + (long)row * 256 + (cb << 4)) = *(const uint4*)(smem + lb);
  }
}

// ------------- softmax over causal prefix, compact bf16 128-tiles -----------
__global__ __launch_bounds__(256) void softmax_tri(char* __restrict__ base) {
  const int r = blockIdx.x;
  const int bz = blockIdx.y;
  const int bm = r >> 7;
  const int w = (bm + 1) << 7;
  char* bb = base + (long)bz * BATCH_B +
             (long)(bm * (bm + 1) / 2) * TILE_B + (long)(r & 127) * 256;
  const int t = threadIdx.x;
  const bool act = (t << 3) < w;
  const int bn = t >> 4;
  const int cl = (t << 3) & 127;
  char* slot = bb + (long)bn * TILE_B + (long)cl * 2;
  float v[8];
  float m = -3.0e38f;
  if (act) {
    ushort4 u0 = ((const ushort4*)slot)[0];
    ushort4 u1 = ((const ushort4*)slot)[1];
    v[0] = bf2f(u0.x); v[1] = bf2f(u0.y); v[2] = bf2f(u0.z); v[3] = bf2f(u0.w);
    v[4] = bf2f(u1.x); v[5] = bf2f(u1.y); v[6] = bf2f(u1.z); v[7] = bf2f(u1.w);
#pragma unroll
    for (int k = 0; k < 8; ++k) m = fmaxf(m, v[k]);
  }
  __shared__ float red[8];
#pragma unroll
  for (int off = 32; off > 0; off >>= 1) m = fmaxf(m, __shfl_down(m, off, 64));
  const int wid = t >> 6, lane = t & 63;
  if (lane == 0) red[wid] = m;
  __syncthreads();
  m = fmaxf(fmaxf(red[0], red[1]), fmaxf(red[2], red[3]));
  float e[8];
  float s = 0.f;
  if (act) {
#pragma unroll
    for (int k = 0; k < 8; ++k) { e[k] = __expf(v[k] - m); s += e[k]; }
  }
#pragma unroll
  for (int off = 32; off > 0; off >>= 1) s += __shfl_down(s, off, 64);
  if (lane == 0) red[4 + wid] = s;
  __syncthreads();
  s = red[4] + red[5] + red[6] + red[7];
  const float inv = 1.0f / s;
  if (act) {
    ushort4 o0, o1;
    o0.x = f2bf(e[0] * inv); o0.y = f2bf(e[1] * inv);
    o0.z = f2bf(e[2] * inv); o0.w = f2bf(e[3] * inv);
    o1.x = f2bf(e[4] * inv); o1.y = f2bf(e[5] * inv);
    o1.z = f2bf(e[6] * inv); o1.w = f2bf(e[7] * inv);
    ((ushort4*)slot)[0] = o0;
    ((ushort4*)slot)[1] = o1;
  }
}

// -------- 128x128 ring-4 swizzled core: PV (causal K-limit, 256B slots) -----
__global__ __launch_bounds__(256, 2) void gemm_pv(
    const char* __restrict__ attn, const unsigned short* __restrict__ VtB,
    float* __restrict__ Out) {
  __shared__ __align__(16) char smem[65536];
  const int tid = threadIdx.x;
  const int wave = tid >> 6, lane = tid & 63;
  const int wr = wave >> 1, wc = wave & 1;
  const int l15 = lane & 15, l4 = lane >> 4;
  const int bz = blockIdx.z;
  const int bm = 15 - blockIdx.x;
  const int bn = blockIdx.y;

  const char* Ab = attn + (long)bz * BATCH_B + (long)(bm * (bm + 1) / 2) * TILE_B;
  const unsigned short* B = VtB + (long)bz * SS * HH;

  const int s0 = tid, s1 = tid + 256;
  const int rA0 = ((s0 >> 3) << 1) | (((s0 >> 2) & 1) ^ ((s0 >> 4) & 1));
  const int cA0 = (s0 & 3) ^ (rA0 & 3);
  const int rA1 = ((s1 >> 3) << 1) | (((s1 >> 2) & 1) ^ ((s1 >> 4) & 1));
  const int cA1 = (s1 & 3) ^ (rA1 & 3);
  const char* aB0 = Ab + (long)rA0 * 256 + cA0 * 16;
  const char* aB1 = Ab + (long)rA1 * 256 + cA1 * 16;
  const char* bG0 = (const char*)(B + (long)(bn * 128 + rA0) * SS) + cA0 * 16;
  const char* bG1 = (const char*)(B + (long)(bn * 128 + rA1) * SS) + cA1 * 16;
  const int ldsL0 = wave << 10;
  const int ldsL1 = 4096 + (wave << 10);

#define STGPV(t_) do { \
    char* _p = smem + (((t_) & 3) << 14); \
    const long _aO = (long)((t_) >> 2) * TILE_B + (long)((t_) & 3) * 64; \
    const long _bO = (long)(t_) << 6; \
    gl_lds16(aB0 + _aO, _p + ldsL0); \
    gl_lds16(aB1 + _aO, _p + ldsL1); \
    gl_lds16(bG0 + _bO, _p + 8192 + ldsL0); \
    gl_lds16(bG1 + _bO, _p + 8192 + ldsL1); } while (0)

  const int baseSwz = ((l15 * 64 + (l4 << 4)) ^ ((l15 & 7) << 4));
  const int rdA = (wr << 12) + baseSwz;
  const int rdB = 8192 + (wc << 12) + baseSwz;

  f32x4 acc[4][4];
  const f32x4 z4 = {0.f, 0.f, 0.f, 0.f};
#pragma unroll
  for (int m = 0; m < 4; ++m)
#pragma unroll
    for (int n = 0; n < 4; ++n) acc[m][n] = z4;

  STGPV(0); STGPV(1); STGPV(2);
  asm volatile("s_waitcnt vmcnt(8)" ::: "memory");
  __builtin_amdgcn_s_barrier();
  __builtin_amdgcn_sched_barrier(0);

  const int kT = (bm + 1) * 4;
  for (int t = 0; t < kT; ++t) {
    if (t + 3 < kT) STGPV(t + 3);
    const char* bufp = smem + ((t & 3) << 14);
    bf16x8 af[4], bg[4];
#pragma unroll
    for (int m = 0; m < 4; ++m)
      af[m] = *(const bf16x8*)(bufp + rdA + (m << 10));
#pragma unroll
    for (int n = 0; n < 4; ++n)
      bg[n] = *(const bf16x8*)(bufp + rdB + (n << 10));
    __builtin_amdgcn_s_setprio(1);
#pragma unroll
    for (int m = 0; m < 4; ++m)
#pragma unroll
      for (int n = 0; n < 4; ++n)
        acc[m][n] = __builtin_amdgcn_mfma_f32_16x16x32_bf16(af[m], bg[n],
                                                            acc[m][n], 0, 0, 0);
    __builtin_amdgcn_s_setprio(0);
    __builtin_amdgcn_sched_barrier(0);
    if (t + 3 < kT)       asm volatile("s_waitcnt vmcnt(8)" ::: "memory");
    else if (t + 3 == kT) asm volatile("s_waitcnt vmcnt(4)" ::: "memory");
    else if (t + 2 == kT) asm volatile("s_waitcnt vmcnt(0)" ::: "memory");
    if (t + 1 < kT) {
      __builtin_amdgcn_s_barrier();
      __builtin_amdgcn_sched_barrier(0);
      asm volatile("" ::: "memory");
    }
  }
#undef STGPV

  const int rl0 = (wr << 6) + (l4 << 2);
  const int cl0 = (wc << 6) + l15;
  __syncthreads();
#pragma unroll
  for (int m = 0; m < 4; ++m)
#pragma unroll
    for (int r = 0; r < 4; ++r) {
      const int ql = rl0 + m * 16 + r;
#pragma unroll
      for (int n = 0; n < 4; ++n) {
        const int colx = (cl0 + n * 16) ^ (l4 << 4);
        *(float*)(smem + ql * 512 + colx * 4) = acc[m][n][r];
      }
    }
  __syncthreads();
  char* Ob = (char*)(Out + ((long)bz * SS + bm * 128) * HH + bn * 128);
#pragma unroll
  for (int i = 0; i < 16; ++i) {
    const int s2 = i * 256 + tid;
    const int row = s2 >> 5;
    const int cb = s2 & 31;
    const int lb = (row * 512 + (cb << 4)) ^ (((row >> 2) & 3) << 6);
    *(uint4*)(Ob + (long)row * 4096 + (cb << 4)) = *(const uint4*)(smem + lb);
  }
}

extern "C" void kernel_launch(void* const* d_in, const int* in_sizes, int n_in,
                              void* d_out, int out_size, void* d_ws, size_t ws_size,
                              hipStream_t stream) {
  (void)in_sizes; (void)n_in; (void)out_size; (void)ws_size;
  const float* x = (const float*)d_in[0];
  const unsigned char* mask_raw = (const unsigned char*)d_in[1];
  const float* Wq = (const float*)d_in[2];
  const float* bq = (const float*)d_in[3];
  const float* Wk = (const float*)d_in[4];
  const float* bk = (const float*)d_in[5];
  const float* Wv = (const float*)d_in[6];
  const float* bv = (const float*)d_in[7];
  char* ws = (char*)d_ws;

  unsigned short* Xbf = (unsigned short*)(ws + OFF_XBF);
  unsigned short* Wbf = (unsigned short*)(ws + OFF_WBF);
  unsigned short* Qb = (unsigned short*)(ws + OFF_Q);
  unsigned short* Kb = (unsigned short*)(ws + OFF_K);
  unsigned short* Vt = (unsigned short*)(ws + OFF_VT);
  unsigned char* mask = (unsigned char*)(ws + OFF_MASK);
  float* meanV = (float*)(ws + OFF_MEANV);

  const long MS = (long)BB * SS;  // 16384

  (void)hipFuncSetAttribute((const void*)gemm256,
                            hipFuncAttributeMaxDynamicSharedMemorySize, 131072);

  // 0. canonicalize mask
  canon_mask<<<1, 256, 0, stream>>>(mask_raw, mask, (int)(BB * SS));

  // 1. fp32 -> bf16
  cvt_f32_bf16<<<2048, 256, 0, stream>>>(x, Xbf, (int)(MS * HH / 4));
  cvt_w3<<<dim3(256, 3), 256, 0, stream>>>(Wq, Wk, Wv, Wbf);

  // 2. fused QKV projection; z==2 writes Vt directly (transposed epilogue)
  gemm256<<<dim3(MS / 256, HH / 256, 3), 512, 131072, stream>>>(
      Xbf, Wbf, (long)HH * HH,
      (char*)Qb, (char*)Kb, (char*)Vt, bq, bk, bv);

  // 3. column sums of V (from Vt) for masked-row fixup
  meanv_sum<<<dim3(HH / 4, BB), 256, 0, stream>>>(Vt, meanV);

  // 4. scores: 128^2 triangular tiles -> compact bf16: grid (136,8)
  gemm128s<<<dim3(NTRI, BB), 256, 0, stream>>>(
      Qb, Kb, ws + OFF_SCORES, mask);

  // 5. softmax over causal prefix, in-place bf16
  softmax_tri<<<dim3(SS, BB), 256, 0, stream>>>(ws + OFF_SCORES);

  // 6. out = attn @ V (compact bf16 A, causal K-limit, longest-first)
  gemm_pv<<<dim3(SS / 128, HH / 128, BB), 256, 0, stream>>>(
      ws + OFF_SCORES, Vt, (float*)d_out);

  // 7. masked query rows -> uniform mean of V
  fixup_masked<<<BB * SS, 256, 0, stream>>>((float*)d_out, mask, meanV);
}

// Round 9
// 313.356 us; speedup vs baseline: 1.4357x; 1.1480x over previous
//
#include <hip/hip_runtime.h>
#include <stdint.h>

typedef __bf16 bf16x8 __attribute__((ext_vector_type(8)));
typedef float f32x4 __attribute__((ext_vector_type(4)));

#define BB 8
#define SS 2048
#define HH 1024

// compact triangular scores: 128x128 tiles, bf16 throughout.
// row slot = 256B. 16x16 grid -> 136 lower tiles per batch.
#define TILE_B   32768ll
#define NTRI     136
#define BATCH_B  (NTRI * TILE_B)   // 4,456,448 B per batch

// ws layout (bytes). Peak ~140 MiB (validated r8).
#define OFF_Q      0ll
#define OFF_K      33554432ll
#define OFF_VT     67108864ll
#define OFF_MASK   100663296ll
#define OFF_MEANV  100679680ll
#define OFF_TMP    101711872ll
#define OFF_XBF    (OFF_TMP)
#define OFF_WBF    (OFF_TMP + 33554432ll)
#define OFF_SCORES (OFF_TMP)

__device__ __forceinline__ unsigned short f2bf(float f) {
  unsigned int u = __float_as_uint(f);
  u += 0x7FFFu + ((u >> 16) & 1u);   // RTNE
  return (unsigned short)(u >> 16);
}
__device__ __forceinline__ float bf2f(unsigned short u) {
  return __uint_as_float(((unsigned int)u) << 16);
}

__device__ __forceinline__ void gl_lds16(const void* g, void* l) {
  __builtin_amdgcn_global_load_lds(
      (const __attribute__((address_space(1))) void*)g,
      (__attribute__((address_space(3))) void*)l, 16, 0, 0);
}

// ------- mask canonicalizer (uint8 / int32 / float32), 1024-thr vectorized --
__global__ __launch_bounds__(1024) void canon_mask(
    const unsigned char* __restrict__ m, unsigned char* __restrict__ out) {
  __shared__ int cnt[4];
  const int t = threadIdx.x;
  if (t < 4) cnt[t] = 0;
  __syncthreads();
  // detection: 1024 threads x 16B covers the full 16384-byte window
  uint4 v = ((const uint4*)m)[t];
  const unsigned char* pb = (const unsigned char*)&v;
  int loc[4] = {0, 0, 0, 0};
#pragma unroll
  for (int j = 0; j < 16; ++j)
    if (pb[j]) loc[j & 3]++;
#pragma unroll
  for (int r = 0; r < 4; ++r)
    if (loc[r]) atomicAdd(&cnt[r], loc[r]);
  __syncthreads();
  const int c0 = cnt[0], c1 = cnt[1], c2 = cnt[2], c3 = cnt[3];
  unsigned char ob[16];
  if (c0 > 0 && c1 == 0 && c2 == 0 && c3 == 0) {        // int32 0/1
    const int* mi = (const int*)m;
#pragma unroll
    for (int j = 0; j < 16; ++j) ob[j] = mi[t * 16 + j] ? 1 : 0;
  } else if (c0 == 0 && (c2 > 0 || c3 > 0)) {           // float32
    const float* mf = (const float*)m;
#pragma unroll
    for (int j = 0; j < 16; ++j) ob[j] = (mf[t * 16 + j] != 0.0f) ? 1 : 0;
  } else {                                              // uint8 bool
#pragma unroll
    for (int j = 0; j < 16; ++j) ob[j] = pb[j] ? 1 : 0;
  }
  ((uint4*)out)[t] = *(const uint4*)ob;
}

__global__ void cvt_f32_bf16(const float* __restrict__ in,
                             unsigned short* __restrict__ out, int n4) {
  int i = blockIdx.x * blockDim.x + threadIdx.x;
  int stride = gridDim.x * blockDim.x;
  for (; i < n4; i += stride) {
    float4 v = ((const float4*)in)[i];
    ushort4 o;
    o.x = f2bf(v.x); o.y = f2bf(v.y); o.z = f2bf(v.z); o.w = f2bf(v.w);
    ((ushort4*)out)[i] = o;
  }
}

__global__ void cvt_w3(const float* __restrict__ Wq, const float* __restrict__ Wk,
                       const float* __restrict__ Wv, unsigned short* __restrict__ out) {
  const int z = blockIdx.y;
  const float* src = (z == 0) ? Wq : (z == 1) ? Wk : Wv;
  unsigned short* dst = out + (long)z * (HH * HH);
  const int n4 = HH * HH / 4;
  int i = blockIdx.x * 256 + threadIdx.x;
  for (; i < n4; i += 256 * 256) {
    float4 v = ((const float4*)src)[i];
    ushort4 o;
    o.x = f2bf(v.x); o.y = f2bf(v.y); o.z = f2bf(v.z); o.w = f2bf(v.w);
    ((ushort4*)dst)[i] = o;
  }
}

__global__ __launch_bounds__(256) void meanv_sum(
    const unsigned short* __restrict__ Vt, float* __restrict__ out) {
  const int b = blockIdx.y;
  const int wave = threadIdx.x >> 6, lane = threadIdx.x & 63;
  const int h = blockIdx.x * 4 + wave;
  const unsigned short* row = Vt + ((long)b * HH + h) * SS;
  float s = 0.f;
#pragma unroll
  for (int j = 0; j < 4; ++j) {
    const ushort4* p = (const ushort4*)(row + j * 512 + lane * 8);
    ushort4 u0 = p[0], u1 = p[1];
    s += bf2f(u0.x) + bf2f(u0.y) + bf2f(u0.z) + bf2f(u0.w)
       + bf2f(u1.x) + bf2f(u1.y) + bf2f(u1.z) + bf2f(u1.w);
  }
#pragma unroll
  for (int off = 32; off > 0; off >>= 1) s += __shfl_down(s, off, 64);
  if (lane == 0) out[(long)b * HH + h] = s;
}

// ============ 256x256 fused QKV — 8-phase schedule (r7-verified core) =======
// bz==2 writes Vt via WRITE-side transposed LDS bounce (r9: fixes the 32-way
// bank conflict of r8's read-side gather).
__global__ __launch_bounds__(512, 2) void gemm256(
    const unsigned short* __restrict__ Abase,
    const unsigned short* __restrict__ Bbase, long bStride,
    char* __restrict__ Cq, char* __restrict__ Ck, char* __restrict__ VtOut,
    const float* __restrict__ biasq, const float* __restrict__ biask,
    const float* __restrict__ biasv) {
  extern __shared__ char smem[];
  const int tid = threadIdx.x;
  const int wave = tid >> 6, lane = tid & 63;
  const int wr = wave >> 2, wc = wave & 3;
  const int l15 = lane & 15, l4 = lane >> 4;
  const int bz = blockIdx.z;
  const int bm = blockIdx.x, bn = blockIdx.y;

  const char* A = (const char*)Abase;
  const char* B = (const char*)(Bbase + (long)bz * bStride);

  const int srow = tid >> 3;
  const int gslot = (tid & 7) ^ (srow & 7);
  const char* gA = A + ((long)bm * 256 + srow) * 2048 + gslot * 16;
  const char* gB = B + ((long)bn * 256 + srow) * 2048 + gslot * 16;
  const int ldsStageW = wave << 10;

#define STG(kt_, type_, buf_) do { \
    const char* _g = (((type_) < 2) ? gA : gB) + \
                     (((type_) & 1) ? 262144 : 0) + ((long)(kt_) << 7); \
    char* _l = smem + ((buf_) << 16) + (((type_) >> 1) << 15) + \
               (((type_) & 1) << 14) + ldsStageW; \
    gl_lds16(_g, _l); \
    gl_lds16(_g + 131072, _l + 8192); } while (0)

  const int sw0 = ((l4 ^ (l15 & 7)) << 4);
  const int sw1 = (((4 + l4) ^ (l15 & 7)) << 4);
  const int aB0 = (wr << 14) + l15 * 128 + sw0;
  const int aB1 = (wr << 14) + l15 * 128 + sw1;
  const int bB0 = 32768 + ((wc >> 1) << 14) + (((wc & 1) << 6) + l15) * 128 + sw0;
  const int bB1 = 32768 + ((wc >> 1) << 14) + (((wc & 1) << 6) + l15) * 128 + sw1;

  f32x4 acc[8][4];
  const f32x4 z4 = {0.f, 0.f, 0.f, 0.f};
#pragma unroll
  for (int m = 0; m < 8; ++m)
#pragma unroll
    for (int n = 0; n < 4; ++n) acc[m][n] = z4;

  STG(0, 0, 0); STG(0, 1, 0); STG(0, 2, 0); STG(0, 3, 0);
  STG(1, 0, 1); STG(1, 1, 1); STG(1, 2, 1); STG(1, 3, 1);
  asm volatile("s_waitcnt vmcnt(8)" ::: "memory");
  __builtin_amdgcn_s_barrier();
  __builtin_amdgcn_sched_barrier(0);

  bf16x8 aC[4][2], bLo[2][2], bHi[2][2];

  for (int it = 0; it < 8; ++it) {
#pragma unroll
    for (int g = 0; g < 8; ++g) {
      const int buf = (g < 4) ? 0 : 65536;
      const int q = g & 3;
      if (q == 0) {
#pragma unroll
        for (int mm = 0; mm < 4; ++mm) {
          aC[mm][0] = *(const bf16x8*)(smem + buf + aB0 + mm * 2048);
          aC[mm][1] = *(const bf16x8*)(smem + buf + aB1 + mm * 2048);
        }
#pragma unroll
        for (int nn = 0; nn < 2; ++nn) {
          bLo[nn][0] = *(const bf16x8*)(smem + buf + bB0 + nn * 2048);
          bLo[nn][1] = *(const bf16x8*)(smem + buf + bB1 + nn * 2048);
        }
      } else if (q == 1) {
#pragma unroll
        for (int nn = 0; nn < 2; ++nn) {
          bHi[nn][0] = *(const bf16x8*)(smem + buf + bB0 + (2 + nn) * 2048);
          bHi[nn][1] = *(const bf16x8*)(smem + buf + bB1 + (2 + nn) * 2048);
        }
      } else if (q == 2) {
#pragma unroll
        for (int mm = 0; mm < 4; ++mm) {
          aC[mm][0] = *(const bf16x8*)(smem + buf + aB0 + (4 + mm) * 2048);
          aC[mm][1] = *(const bf16x8*)(smem + buf + aB1 + (4 + mm) * 2048);
        }
      }
      {
        const int u = it * 8 + g - 2;
        if (u >= 0) {
          const int kt = 2 + (u >> 2);
          if (kt < 16) {
            if (g == 0)      STG(kt, 0, 1);
            else if (g == 1) STG(kt, 1, 1);
            else if (g == 2) STG(kt, 2, 0);
            else if (g == 3) STG(kt, 3, 0);
            else if (g == 4) STG(kt, 0, 0);
            else if (g == 5) STG(kt, 1, 0);
            else if (g == 6) STG(kt, 2, 1);
            else             STG(kt, 3, 1);
          }
        }
      }
      __builtin_amdgcn_s_barrier();
      asm volatile("s_waitcnt lgkmcnt(0)" ::: "memory");
      __builtin_amdgcn_sched_barrier(0);
      __builtin_amdgcn_s_setprio(1);
      if (q == 0) {
#pragma unroll
        for (int mm = 0; mm < 4; ++mm)
#pragma unroll
          for (int nn = 0; nn < 2; ++nn) {
            acc[mm][nn] = __builtin_amdgcn_mfma_f32_16x16x32_bf16(
                aC[mm][0], bLo[nn][0], acc[mm][nn], 0, 0, 0);
            acc[mm][nn] = __builtin_amdgcn_mfma_f32_16x16x32_bf16(
                aC[mm][1], bLo[nn][1], acc[mm][nn], 0, 0, 0);
          }
      } else if (q == 1) {
#pragma unroll
        for (int mm = 0; mm < 4; ++mm)
#pragma unroll
          for (int nn = 0; nn < 2; ++nn) {
            acc[mm][2 + nn] = __builtin_amdgcn_mfma_f32_16x16x32_bf16(
                aC[mm][0], bHi[nn][0], acc[mm][2 + nn], 0, 0, 0);
            acc[mm][2 + nn] = __builtin_amdgcn_mfma_f32_16x16x32_bf16(
                aC[mm][1], bHi[nn][1], acc[mm][2 + nn], 0, 0, 0);
          }
      } else if (q == 2) {
#pragma unroll
        for (int mm = 0; mm < 4; ++mm)
#pragma unroll
          for (int nn = 0; nn < 2; ++nn) {
            acc[4 + mm][2 + nn] = __builtin_amdgcn_mfma_f32_16x16x32_bf16(
                aC[mm][0], bHi[nn][0], acc[4 + mm][2 + nn], 0, 0, 0);
            acc[4 + mm][2 + nn] = __builtin_amdgcn_mfma_f32_16x16x32_bf16(
                aC[mm][1], bHi[nn][1], acc[4 + mm][2 + nn], 0, 0, 0);
          }
      } else {
#pragma unroll
        for (int mm = 0; mm < 4; ++mm)
#pragma unroll
          for (int nn = 0; nn < 2; ++nn) {
            acc[4 + mm][nn] = __builtin_amdgcn_mfma_f32_16x16x32_bf16(
                aC[mm][0], bLo[nn][0], acc[4 + mm][nn], 0, 0, 0);
            acc[4 + mm][nn] = __builtin_amdgcn_mfma_f32_16x16x32_bf16(
                aC[mm][1], bLo[nn][1], acc[4 + mm][nn], 0, 0, 0);
          }
      }
      __builtin_amdgcn_s_setprio(0);
      __builtin_amdgcn_sched_barrier(0);
      if (q == 3) {
        if (g == 3 && it == 7)
          asm volatile("s_waitcnt vmcnt(0)" ::: "memory");
        else
          asm volatile("s_waitcnt vmcnt(4)" ::: "memory");
      }
      __builtin_amdgcn_s_barrier();
      asm volatile("" ::: "memory");
    }
  }
#undef STG

  const int rl0 = (wr << 7) + (l4 << 2);
  const int cl0 = (wc << 6) + l15;

  if (bz < 2) {
    // ---- row-major bounce (r7-verified) ----
    const float* bias = (bz == 0) ? biasq : biask;
#pragma unroll
    for (int n = 0; n < 4; ++n) {
      const int cl = cl0 + n * 16;
      const float bv = bias[bn * 256 + cl];
      const int colx = cl ^ (l4 << 4);
#pragma unroll
      for (int m = 0; m < 8; ++m) {
        const int rl = rl0 + m * 16;
#pragma unroll
        for (int r = 0; r < 4; ++r)
          *(unsigned short*)(smem + (rl + r) * 512 + colx * 2) =
              f2bf(acc[m][n][r] + bv);
      }
    }
    __syncthreads();
    unsigned short* C = (unsigned short*)((bz == 0) ? Cq : Ck);
    const long rowg0 = (long)bm * 256;
    const long colb0 = (long)bn * 512;
#pragma unroll
    for (int i = 0; i < 16; ++i) {
      const int s2 = i * 512 + tid;
      const int row = s2 >> 5;
      const int cb = s2 & 31;
      const int lb = (row * 512 + (cb << 4)) ^ (((row >> 2) & 3) << 5);
      *(uint4*)((char*)C + (rowg0 + row) * 2048 + colb0 + (cb << 4)) =
          *(const uint4*)(smem + lb);
    }
  } else {
    // ---- WRITE-side transposed bounce: LDS = [h=256][512B], swizzled ----
    // thread holds C[s][h]; pack 4 consecutive s per (m,n) -> one 8B store.
#pragma unroll
    for (int n = 0; n < 4; ++n) {
      const int h = cl0 + n * 16;
      const float bv = biasv[bn * 256 + h];
      const int xr = (h & 7) << 4;
#pragma unroll
      for (int m = 0; m < 8; ++m) {
        const int s0a = rl0 + m * 16;
        uint2 w;
        w.x = (unsigned)f2bf(acc[m][n][0] + bv) |
              ((unsigned)f2bf(acc[m][n][1] + bv) << 16);
        w.y = (unsigned)f2bf(acc[m][n][2] + bv) |
              ((unsigned)f2bf(acc[m][n][3] + bv) << 16);
        *(uint2*)(smem + h * 512 + ((s0a * 2) ^ xr)) = w;
      }
    }
    __syncthreads();
    char* VtB = VtOut + (long)(bm >> 3) * (SS * HH * 2) + (long)(bm & 7) * 512;
#pragma unroll
    for (int i = 0; i < 16; ++i) {
      const int s2 = i * 512 + tid;
      const int h = s2 >> 5;
      const int cb = s2 & 31;
      const int lb = h * 512 + ((cb << 4) ^ ((h & 7) << 4));
      *(uint4*)(VtB + (long)(bn * 256 + h) * 4096 + cb * 16) =
          *(const uint4*)(smem + lb);
    }
  }
}

// -------- 128x128 ring-4 swizzled core: SCORES -> compact bf16 --------------
__global__ __launch_bounds__(256, 2) void gemm128s(
    const unsigned short* __restrict__ Qb, const unsigned short* __restrict__ Kb,
    char* __restrict__ scoresBase, const unsigned char* __restrict__ maskg) {
  __shared__ __align__(16) char smem[65536];
  const int tid = threadIdx.x;
  const int wave = tid >> 6, lane = tid & 63;
  const int wr = wave >> 1, wc = wave & 1;
  const int l15 = lane & 15, l4 = lane >> 4;
  const int bz = blockIdx.y;

  int t0 = blockIdx.x, bm = 0, a_ = 0;
  while (a_ + bm + 1 <= t0) { ++bm; a_ += bm; }
  const int bn = t0 - a_;

  const unsigned short* A = Qb + (long)bz * SS * HH;
  const unsigned short* B = Kb + (long)bz * SS * HH;

  const int s0 = tid, s1 = tid + 256;
  const int rA0 = ((s0 >> 3) << 1) | (((s0 >> 2) & 1) ^ ((s0 >> 4) & 1));
  const int cA0 = (s0 & 3) ^ (rA0 & 3);
  const int rA1 = ((s1 >> 3) << 1) | (((s1 >> 2) & 1) ^ ((s1 >> 4) & 1));
  const int cA1 = (s1 & 3) ^ (rA1 & 3);
  const char* aG0 = (const char*)A + (long)(bm * 128 + rA0) * 2048 + cA0 * 16;
  const char* aG1 = (const char*)A + (long)(bm * 128 + rA1) * 2048 + cA1 * 16;
  const char* bG0 = (const char*)B + (long)(bn * 128 + rA0) * 2048 + cA0 * 16;
  const char* bG1 = (const char*)B + (long)(bn * 128 + rA1) * 2048 + cA1 * 16;
  const int ldsL0 = wave << 10;
  const int ldsL1 = 4096 + (wave << 10);

#define STG(t_) do { \
    char* _p = smem + (((t_) & 3) << 14); \
    const long _ko = (long)(t_) << 6; \
    gl_lds16(aG0 + _ko, _p + ldsL0); \
    gl_lds16(aG1 + _ko, _p + ldsL1); \
    gl_lds16(bG0 + _ko, _p + 8192 + ldsL0); \
    gl_lds16(bG1 + _ko, _p + 8192 + ldsL1); } while (0)

  const int baseSwz = ((l15 * 64 + (l4 << 4)) ^ ((l15 & 7) << 4));
  const int rdA = (wr << 12) + baseSwz;
  const int rdB = 8192 + (wc << 12) + baseSwz;

  f32x4 acc[4][4];
  const f32x4 z4 = {0.f, 0.f, 0.f, 0.f};
#pragma unroll
  for (int m = 0; m < 4; ++m)
#pragma unroll
    for (int n = 0; n < 4; ++n) acc[m][n] = z4;

  STG(0); STG(1); STG(2);
  asm volatile("s_waitcnt vmcnt(8)" ::: "memory");
  __builtin_amdgcn_s_barrier();
  __builtin_amdgcn_sched_barrier(0);

  const int kT = 32;
  for (int t = 0; t < kT; ++t) {
    if (t + 3 < kT) STG(t + 3);
    const char* bufp = smem + ((t & 3) << 14);
    bf16x8 af[4], bg[4];
#pragma unroll
    for (int m = 0; m < 4; ++m)
      af[m] = *(const bf16x8*)(bufp + rdA + (m << 10));
#pragma unroll
    for (int n = 0; n < 4; ++n)
      bg[n] = *(const bf16x8*)(bufp + rdB + (n << 10));
    __builtin_amdgcn_s_setprio(1);
#pragma unroll
    for (int m = 0; m < 4; ++m)
#pragma unroll
      for (int n = 0; n < 4; ++n)
        acc[m][n] = __builtin_amdgcn_mfma_f32_16x16x32_bf16(af[m], bg[n],
                                                            acc[m][n], 0, 0, 0);
    __builtin_amdgcn_s_setprio(0);
    __builtin_amdgcn_sched_barrier(0);
    if (t + 3 < kT)       asm volatile("s_waitcnt vmcnt(8)" ::: "memory");
    else if (t + 3 == kT) asm volatile("s_waitcnt vmcnt(4)" ::: "memory");
    else if (t + 2 == kT) asm volatile("s_waitcnt vmcnt(0)" ::: "memory");
    if (t + 1 < kT) {
      __builtin_amdgcn_s_barrier();
      __builtin_amdgcn_sched_barrier(0);
      asm volatile("" ::: "memory");
    }
  }
#undef STG

  const int rl0 = (wr << 6) + (l4 << 2);
  const int cl0 = (wc << 6) + l15;
  char* Ct = scoresBase + (long)bz * BATCH_B + (long)t0 * TILE_B;
  const unsigned char* mrow = maskg + (long)bz * SS;
  bool km[4]; int kg[4];
#pragma unroll
  for (int n = 0; n < 4; ++n) {
    kg[n] = bn * 128 + cl0 + n * 16;
    km[n] = mrow[kg[n]] != 0;
  }
  __syncthreads();
#pragma unroll
  for (int m = 0; m < 4; ++m)
#pragma unroll
    for (int r = 0; r < 4; ++r) {
      const int ql = rl0 + m * 16 + r;
      const int q = bm * 128 + ql;
      const bool qm = mrow[q] != 0;
#pragma unroll
      for (int n = 0; n < 4; ++n) {
        float v;
        if (!qm) v = 0.0f;
        else if (kg[n] <= q && km[n]) v = acc[m][n][r] * 0.03125f;
        else v = -1.0e9f;
        const int colx = (cl0 + n * 16) ^ (l4 << 4);
        *(unsigned short*)(smem + ql * 256 + colx * 2) = f2bf(v);
      }
    }
  __syncthreads();
#pragma unroll
  for (int i = 0; i < 8; ++i) {
    const int s2 = i * 256 + tid;
    const int row = s2 >> 4;
    const int cb = s2 & 15;
    const int lb = row * 256 + ((cb << 4) ^ (((row >> 2) & 3) << 5));
    *(uint4*)(Ct + (long)row * 256 + (cb << 4)) = *(const uint4*)(smem + lb);
  }
}

// ------------- softmax over causal prefix, compact bf16 128-tiles -----------
__global__ __launch_bounds__(256) void softmax_tri(char* __restrict__ base) {
  const int r = blockIdx.x;
  const int bz = blockIdx.y;
  const int bm = r >> 7;
  const int w = (bm + 1) << 7;
  char* bb = base + (long)bz * BATCH_B +
             (long)(bm * (bm + 1) / 2) * TILE_B + (long)(r & 127) * 256;
  const int t = threadIdx.x;
  const bool act = (t << 3) < w;
  const int bn = t >> 4;
  const int cl = (t << 3) & 127;
  char* slot = bb + (long)bn * TILE_B + (long)cl * 2;
  float v[8];
  float m = -3.0e38f;
  if (act) {
    ushort4 u0 = ((const ushort4*)slot)[0];
    ushort4 u1 = ((const ushort4*)slot)[1];
    v[0] = bf2f(u0.x); v[1] = bf2f(u0.y); v[2] = bf2f(u0.z); v[3] = bf2f(u0.w);
    v[4] = bf2f(u1.x); v[5] = bf2f(u1.y); v[6] = bf2f(u1.z); v[7] = bf2f(u1.w);
#pragma unroll
    for (int k = 0; k < 8; ++k) m = fmaxf(m, v[k]);
  }
  __shared__ float red[8];
#pragma unroll
  for (int off = 32; off > 0; off >>= 1) m = fmaxf(m, __shfl_down(m, off, 64));
  const int wid = t >> 6, lane = t & 63;
  if (lane == 0) red[wid] = m;
  __syncthreads();
  m = fmaxf(fmaxf(red[0], red[1]), fmaxf(red[2], red[3]));
  float e[8];
  float s = 0.f;
  if (act) {
#pragma unroll
    for (int k = 0; k < 8; ++k) { e[k] = __expf(v[k] - m); s += e[k]; }
  }
#pragma unroll
  for (int off = 32; off > 0; off >>= 1) s += __shfl_down(s, off, 64);
  if (lane == 0) red[4 + wid] = s;
  __syncthreads();
  s = red[4] + red[5] + red[6] + red[7];
  const float inv = 1.0f / s;
  if (act) {
    ushort4 o0, o1;
    o0.x = f2bf(e[0] * inv); o0.y = f2bf(e[1] * inv);
    o0.z = f2bf(e[2] * inv); o0.w = f2bf(e[3] * inv);
    o1.x = f2bf(e[4] * inv); o1.y = f2bf(e[5] * inv);
    o1.z = f2bf(e[6] * inv); o1.w = f2bf(e[7] * inv);
    ((ushort4*)slot)[0] = o0;
    ((ushort4*)slot)[1] = o1;
  }
}

// -------- 128x128 ring-4 swizzled core: PV + fused masked-row fixup ---------
__global__ __launch_bounds__(256, 2) void gemm_pv(
    const char* __restrict__ attn, const unsigned short* __restrict__ VtB,
    float* __restrict__ Out, const unsigned char* __restrict__ maskg,
    const float* __restrict__ meanV) {
  __shared__ __align__(16) char smem[65536];
  const int tid = threadIdx.x;
  const int wave = tid >> 6, lane = tid & 63;
  const int wr = wave >> 1, wc = wave & 1;
  const int l15 = lane & 15, l4 = lane >> 4;
  const int bz = blockIdx.z;
  const int bm = 15 - blockIdx.x;
  const int bn = blockIdx.y;

  const char* Ab = attn + (long)bz * BATCH_B + (long)(bm * (bm + 1) / 2) * TILE_B;
  const unsigned short* B = VtB + (long)bz * SS * HH;

  const int s0 = tid, s1 = tid + 256;
  const int rA0 = ((s0 >> 3) << 1) | (((s0 >> 2) & 1) ^ ((s0 >> 4) & 1));
  const int cA0 = (s0 & 3) ^ (rA0 & 3);
  const int rA1 = ((s1 >> 3) << 1) | (((s1 >> 2) & 1) ^ ((s1 >> 4) & 1));
  const int cA1 = (s1 & 3) ^ (rA1 & 3);
  const char* aB0 = Ab + (long)rA0 * 256 + cA0 * 16;
  const char* aB1 = Ab + (long)rA1 * 256 + cA1 * 16;
  const char* bG0 = (const char*)(B + (long)(bn * 128 + rA0) * SS) + cA0 * 16;
  const char* bG1 = (const char*)(B + (long)(bn * 128 + rA1) * SS) + cA1 * 16;
  const int ldsL0 = wave << 10;
  const int ldsL1 = 4096 + (wave << 10);

#define STGPV(t_) do { \
    char* _p = smem + (((t_) & 3) << 14); \
    const long _aO = (long)((t_) >> 2) * TILE_B + (long)((t_) & 3) * 64; \
    const long _bO = (long)(t_) << 6; \
    gl_lds16(aB0 + _aO, _p + ldsL0); \
    gl_lds16(aB1 + _aO, _p + ldsL1); \
    gl_lds16(bG0 + _bO, _p + 8192 + ldsL0); \
    gl_lds16(bG1 + _bO, _p + 8192 + ldsL1); } while (0)

  const int baseSwz = ((l15 * 64 + (l4 << 4)) ^ ((l15 & 7) << 4));
  const int rdA = (wr << 12) + baseSwz;
  const int rdB = 8192 + (wc << 12) + baseSwz;

  f32x4 acc[4][4];
  const f32x4 z4 = {0.f, 0.f, 0.f, 0.f};
#pragma unroll
  for (int m = 0; m < 4; ++m)
#pragma unroll
    for (int n = 0; n < 4; ++n) acc[m][n] = z4;

  STGPV(0); STGPV(1); STGPV(2);
  asm volatile("s_waitcnt vmcnt(8)" ::: "memory");
  __builtin_amdgcn_s_barrier();
  __builtin_amdgcn_sched_barrier(0);

  const int kT = (bm + 1) * 4;
  for (int t = 0; t < kT; ++t) {
    if (t + 3 < kT) STGPV(t + 3);
    const char* bufp = smem + ((t & 3) << 14);
    bf16x8 af[4], bg[4];
#pragma unroll
    for (int m = 0; m < 4; ++m)
      af[m] = *(const bf16x8*)(bufp + rdA + (m << 10));
#pragma unroll
    for (int n = 0; n < 4; ++n)
      bg[n] = *(const bf16x8*)(bufp + rdB + (n << 10));
    __builtin_amdgcn_s_setprio(1);
#pragma unroll
    for (int m = 0; m < 4; ++m)
#pragma unroll
      for (int n = 0; n < 4; ++n)
        acc[m][n] = __builtin_amdgcn_mfma_f32_16x16x32_bf16(af[m], bg[n],
                                                            acc[m][n], 0, 0, 0);
    __builtin_amdgcn_s_setprio(0);
    __builtin_amdgcn_sched_barrier(0);
    if (t + 3 < kT)       asm volatile("s_waitcnt vmcnt(8)" ::: "memory");
    else if (t + 3 == kT) asm volatile("s_waitcnt vmcnt(4)" ::: "memory");
    else if (t + 2 == kT) asm volatile("s_waitcnt vmcnt(0)" ::: "memory");
    if (t + 1 < kT) {
      __builtin_amdgcn_s_barrier();
      __builtin_amdgcn_sched_barrier(0);
      asm volatile("" ::: "memory");
    }
  }
#undef STGPV

  const int rl0 = (wr << 6) + (l4 << 2);
  const int cl0 = (wc << 6) + l15;
  __syncthreads();
#pragma unroll
  for (int m = 0; m < 4; ++m)
#pragma unroll
    for (int r = 0; r < 4; ++r) {
      const int ql = rl0 + m * 16 + r;
#pragma unroll
      for (int n = 0; n < 4; ++n) {
        const int colx = (cl0 + n * 16) ^ (l4 << 4);
        *(float*)(smem + ql * 512 + colx * 4) = acc[m][n][r];
      }
    }
  __syncthreads();
  const unsigned char* mrow = maskg + (long)bz * SS + bm * 128;
  const float* mv = meanV + (long)bz * HH + bn * 128;
  char* Ob = (char*)(Out + ((long)bz * SS + bm * 128) * HH + bn * 128);
#pragma unroll
  for (int i = 0; i < 16; ++i) {
    const int s2 = i * 256 + tid;
    const int row = s2 >> 5;
    const int cb = s2 & 31;
    const int lb = (row * 512 + (cb << 4)) ^ (((row >> 2) & 3) << 6);
    uint4 val = *(const uint4*)(smem + lb);
    if (!mrow[row]) {                       // masked q-row: uniform mean of V
      float4 f = *(const float4*)(mv + cb * 4);
      val.x = __float_as_uint(f.x * (1.f / 2048.f));
      val.y = __float_as_uint(f.y * (1.f / 2048.f));
      val.z = __float_as_uint(f.z * (1.f / 2048.f));
      val.w = __float_as_uint(f.w * (1.f / 2048.f));
    }
    *(uint4*)(Ob + (long)row * 4096 + (cb << 4)) = val;
  }
}

extern "C" void kernel_launch(void* const* d_in, const int* in_sizes, int n_in,
                              void* d_out, int out_size, void* d_ws, size_t ws_size,
                              hipStream_t stream) {
  (void)in_sizes; (void)n_in; (void)out_size; (void)ws_size;
  const float* x = (const float*)d_in[0];
  const unsigned char* mask_raw = (const unsigned char*)d_in[1];
  const float* Wq = (const float*)d_in[2];
  const float* bq = (const float*)d_in[3];
  const float* Wk = (const float*)d_in[4];
  const float* bk = (const float*)d_in[5];
  const float* Wv = (const float*)d_in[6];
  const float* bv = (const float*)d_in[7];
  char* ws = (char*)d_ws;

  unsigned short* Xbf = (unsigned short*)(ws + OFF_XBF);
  unsigned short* Wbf = (unsigned short*)(ws + OFF_WBF);
  unsigned short* Qb = (unsigned short*)(ws + OFF_Q);
  unsigned short* Kb = (unsigned short*)(ws + OFF_K);
  unsigned short* Vt = (unsigned short*)(ws + OFF_VT);
  unsigned char* mask = (unsigned char*)(ws + OFF_MASK);
  float* meanV = (float*)(ws + OFF_MEANV);

  const long MS = (long)BB * SS;  // 16384

  (void)hipFuncSetAttribute((const void*)gemm256,
                            hipFuncAttributeMaxDynamicSharedMemorySize, 131072);

  // 0. canonicalize mask (vectorized single block)
  canon_mask<<<1, 1024, 0, stream>>>(mask_raw, mask);

  // 1. fp32 -> bf16
  cvt_f32_bf16<<<2048, 256, 0, stream>>>(x, Xbf, (int)(MS * HH / 4));
  cvt_w3<<<dim3(256, 3), 256, 0, stream>>>(Wq, Wk, Wv, Wbf);

  // 2. fused QKV projection; z==2 writes Vt (write-side transposed bounce)
  gemm256<<<dim3(MS / 256, HH / 256, 3), 512, 131072, stream>>>(
      Xbf, Wbf, (long)HH * HH,
      (char*)Qb, (char*)Kb, (char*)Vt, bq, bk, bv);

  // 3. column sums of V (from Vt) for masked-row substitution
  meanv_sum<<<dim3(HH / 4, BB), 256, 0, stream>>>(Vt, meanV);

  // 4. scores: 128^2 triangular tiles -> compact bf16: grid (136,8)
  gemm128s<<<dim3(NTRI, BB), 256, 0, stream>>>(
      Qb, Kb, ws + OFF_SCORES, mask);

  // 5. softmax over causal prefix, in-place bf16
  softmax_tri<<<dim3(SS, BB), 256, 0, stream>>>(ws + OFF_SCORES);

  // 6. out = attn @ V with fused masked-row meanV substitution
  gemm_pv<<<dim3(SS / 128, HH / 128, BB), 256, 0, stream>>>(
      ws + OFF_SCORES, Vt, (float*)d_out, mask, meanV);
}